// Round 2
// baseline (2502.997 us; speedup 1.0000x reference)
//
#include <hip/hip_runtime.h>
#include <hip/hip_bf16.h>
#include <math.h>

#define B_ 4
#define H_ 128
#define W_ 128
#define N_ 16384

using bf16 = __hip_bfloat16;

__device__ __forceinline__ float toF(float v) { return v; }
__device__ __forceinline__ float toF(bf16 v) { return __bfloat162float(v); }
__device__ __forceinline__ void storeF(float* p, float v) { *p = v; }
__device__ __forceinline__ void storeF(bf16* p, float v) { *p = __float2bfloat16(v); }

// ================= GEMM: Y[b][oc][n] = sum_ic W[oc][ic] * X[b][ic][n] =================
template <typename TX, typename TY>
__global__ __launch_bounds__(256) void gemm1x1(
    const float* __restrict__ W, const TX* __restrict__ X, TY* __restrict__ Y,
    int OC, int IC) {
  int b = blockIdx.z;
  const TX* Xb = X + (size_t)b * IC * N_;
  TY* Yb = Y + (size_t)b * OC * N_;
  int n0 = blockIdx.x * 64;
  int oc0 = blockIdx.y * 64;
  __shared__ float Ws[16][64];
  __shared__ float Xs[16][64];
  int tid = threadIdx.x;
  int tx = tid & 15, ty = tid >> 4;
  float acc[4][4] = {};
  for (int k0 = 0; k0 < IC; k0 += 16) {
#pragma unroll
    for (int i = 0; i < 4; i++) {
      int idx = tid + i * 256;
      int oc = idx >> 4, kw = idx & 15;
      Ws[kw][oc] = W[(size_t)(oc0 + oc) * IC + k0 + kw];
      int kx = idx >> 6, nn = idx & 63;
      Xs[kx][nn] = toF(Xb[(size_t)(k0 + kx) * N_ + n0 + nn]);
    }
    __syncthreads();
#pragma unroll
    for (int kk = 0; kk < 16; kk++) {
      float4 wv = *reinterpret_cast<const float4*>(&Ws[kk][ty * 4]);
      float4 xv = *reinterpret_cast<const float4*>(&Xs[kk][tx * 4]);
      float wa[4] = {wv.x, wv.y, wv.z, wv.w};
      float xa[4] = {xv.x, xv.y, xv.z, xv.w};
#pragma unroll
      for (int i = 0; i < 4; i++)
#pragma unroll
        for (int j = 0; j < 4; j++) acc[i][j] += wa[i] * xa[j];
    }
    __syncthreads();
  }
#pragma unroll
  for (int i = 0; i < 4; i++)
#pragma unroll
    for (int j = 0; j < 4; j++)
      storeF(&Yb[(size_t)(oc0 + ty * 4 + i) * N_ + n0 + tx * 4 + j], acc[i][j]);
}

// ================= LP: adaptive avg pool per region (from bf16 qkv v-channels) ==========
__global__ __launch_bounds__(256) void k_lp_pool(const bf16* __restrict__ qkv,
                                                 float* __restrict__ pools) {
  int b = blockIdx.z, cc = blockIdx.y, r = blockIdx.x;  // r < 36
  int g = cc >> 6;
  const int S[4] = {1, 2, 3, 6};
  int s = S[g];
  if (r >= s * s) return;
  int i = r / s, j = r % s;
  int h0 = (i * H_) / s, h1 = ((i + 1) * H_ + s - 1) / s;
  int w0 = (j * W_) / s, w1 = ((j + 1) * W_ + s - 1) / s;
  int vch = 512 + (cc & 31) * 8 + (cc >> 5);
  const bf16* src = qkv + ((size_t)b * 768 + vch) * N_;
  int wlen = w1 - w0;
  int cnt = (h1 - h0) * wlen;
  float sum = 0.f;
  for (int idx = threadIdx.x; idx < cnt; idx += 256) {
    int yy = h0 + idx / wlen;
    int xx = w0 + idx % wlen;
    sum += toF(src[yy * W_ + xx]);
  }
  __shared__ float red[256];
  red[threadIdx.x] = sum;
  __syncthreads();
  for (int off = 128; off > 0; off >>= 1) {
    if (threadIdx.x < off) red[threadIdx.x] += red[threadIdx.x + off];
    __syncthreads();
  }
  if (threadIdx.x == 0) pools[((size_t)b * 256 + cc) * 36 + r] = red[0] / (float)cnt;
}

// ======== fused: HP depthwise conv + LP bilinear-up(relu) + df = q*HP + LP ========
__global__ __launch_bounds__(256) void k_dffuse(const bf16* __restrict__ qkv,
    const float* __restrict__ pools,
    const float* __restrict__ f3w, const float* __restrict__ f3b,
    const float* __restrict__ f5w, const float* __restrict__ f5b,
    const float* __restrict__ f7w, const float* __restrict__ f7b,
    bf16* __restrict__ df) {
  int b = blockIdx.z, cc = blockIdx.y;
  int n = blockIdx.x * 256 + threadIdx.x;
  int y = n >> 7, x = n & 127;
  int vch = 512 + (cc & 31) * 8 + (cc >> 5);   // v in (d,h) channel decomposition
  const bf16* src = qkv + ((size_t)b * 768 + vch) * N_;
  // ---- HP depthwise conv ----
  int ksz; const float* wp; float bias;
  if (cc < 64)       { ksz = 3; wp = f3w + cc * 9;          bias = f3b[cc]; }
  else if (cc < 160) { ksz = 5; wp = f5w + (cc - 64) * 25;  bias = f5b[cc - 64]; }
  else               { ksz = 7; wp = f7w + (cc - 160) * 49; bias = f7b[cc - 160]; }
  int r = ksz >> 1;
  float hp = bias;
  for (int u = 0; u < ksz; u++) {
    int yy = y + u - r;
    if (yy < 0 || yy >= H_) continue;
    for (int v = 0; v < ksz; v++) {
      int xx = x + v - r;
      if (xx < 0 || xx >= W_) continue;
      hp += toF(src[yy * W_ + xx]) * wp[u * ksz + v];
    }
  }
  // ---- LP bilinear upsample (half-pixel, clamped) + relu ----
  const int S[4] = {1, 2, 3, 6};
  int s = S[cc >> 6];
  const float* pl = pools + ((size_t)b * 256 + cc) * 36;
  float fy = (y + 0.5f) * s * (1.0f / 128.f) - 0.5f;
  float fx = (x + 0.5f) * s * (1.0f / 128.f) - 0.5f;
  int i0 = (int)floorf(fy); float ty = fy - i0;
  int j0 = (int)floorf(fx); float tx = fx - j0;
  int i1 = i0 + 1, j1 = j0 + 1;
  i0 = min(max(i0, 0), s - 1); i1 = min(max(i1, 0), s - 1);
  j0 = min(max(j0, 0), s - 1); j1 = min(max(j1, 0), s - 1);
  float v00 = pl[i0 * s + j0], v01 = pl[i0 * s + j1];
  float v10 = pl[i1 * s + j0], v11 = pl[i1 * s + j1];
  float lp = (1.f - ty) * ((1.f - tx) * v00 + tx * v01) + ty * ((1.f - tx) * v10 + tx * v11);
  lp = fmaxf(lp, 0.f);
  // ---- df = q * HP + LP ----
  int qch = (cc & 31) * 8 + (cc >> 5);   // q in (d,h) decomposition
  float q = toF(qkv[((size_t)b * 768 + qch) * N_ + n]);
  df[((size_t)b * 256 + cc) * N_ + n] = __float2bfloat16(q * hp + lp);
}

// ======== window attention (8x8, rel bias, softmax, apply to df) — img in-place over df ==
__global__ __launch_bounds__(256) void k_attn(const bf16* __restrict__ qkv,
    bf16* __restrict__ df, const float* __restrict__ rel) {
  int b = blockIdx.z, head = blockIdx.y, win = blockIdx.x;
  int wh = win >> 4, wc = win & 15;
  __shared__ float qs[64][33], ks[64][33], ds[64][33];
  __shared__ float pm[64][65];
  __shared__ float bias_s[225];
  int tid = threadIdx.x;
  for (int i = tid; i < 225; i += 256) bias_s[i] = rel[i * 8 + head];
  int dc = tid >> 3, c2 = tid & 7;
  const bf16* qsrc = qkv + ((size_t)b * 768 + head * 32 + dc) * N_;  // (h,d) decomp
  const bf16* ksrc = qkv + ((size_t)b * 768 + 256 + head * 32 + dc) * N_;
  const bf16* dsrc = df + ((size_t)b * 256 + head * 32 + dc) * N_;
#pragma unroll
  for (int r = 0; r < 8; r++) {
    int n = (wh * 8 + r) * W_ + wc * 8 + c2;
    int l = r * 8 + c2;
    qs[l][dc] = toF(qsrc[n]);
    ks[l][dc] = toF(ksrc[n]);
    ds[l][dc] = toF(dsrc[n]);
  }
  __syncthreads();
  int l = tid >> 2, mg = tid & 3;
  int r1 = l >> 3, c1 = l & 7;
  const float scale = 0.17677669529663687f;  // 32^-0.5
  float vals[16];
  float mymax = -1e30f;
#pragma unroll
  for (int mi = 0; mi < 16; mi++) {
    int m = mg * 16 + mi;
    float a = 0.f;
#pragma unroll
    for (int kk = 0; kk < 32; kk++) a += qs[l][kk] * ks[m][kk];
    int r2 = m >> 3, c2m = m & 7;
    a = a * scale + bias_s[(r1 - r2 + 7) * 15 + (c1 - c2m + 7)];
    vals[mi] = a;
    mymax = fmaxf(mymax, a);
  }
  mymax = fmaxf(mymax, __shfl_xor(mymax, 1));
  mymax = fmaxf(mymax, __shfl_xor(mymax, 2));
  float mysum = 0.f;
#pragma unroll
  for (int mi = 0; mi < 16; mi++) { vals[mi] = __expf(vals[mi] - mymax); mysum += vals[mi]; }
  mysum += __shfl_xor(mysum, 1);
  mysum += __shfl_xor(mysum, 2);
  float inv = 1.0f / mysum;
#pragma unroll
  for (int mi = 0; mi < 16; mi++) pm[l][mg * 16 + mi] = vals[mi] * inv;
  __syncthreads();
  int dg = tid & 3;
  float acc[8] = {};
  for (int m = 0; m < 64; m++) {
    float p = pm[l][m];
#pragma unroll
    for (int q2 = 0; q2 < 8; q2++) acc[q2] += p * ds[m][dg * 8 + q2];
  }
  int n = (wh * 8 + r1) * W_ + wc * 8 + c1;
#pragma unroll
  for (int q2 = 0; q2 < 8; q2++)
    df[((size_t)b * 256 + head * 32 + dg * 8 + q2) * N_ + n] = __float2bfloat16(acc[q2]);
}

// ================= CBAM: per-channel max/mean over pixels =================
__global__ __launch_bounds__(256) void k_chstats(const bf16* __restrict__ loc,
    float* __restrict__ mx, float* __restrict__ av) {
  int c = blockIdx.x, b = blockIdx.y;
  const bf16* p = loc + ((size_t)b * 512 + c) * N_;
  float m = -1e30f, s = 0.f;
  for (int i = threadIdx.x; i < N_; i += 256) { float v = toF(p[i]); m = fmaxf(m, v); s += v; }
  __shared__ float rm[256], rs[256];
  rm[threadIdx.x] = m; rs[threadIdx.x] = s;
  __syncthreads();
  for (int off = 128; off > 0; off >>= 1) {
    if (threadIdx.x < off) {
      rm[threadIdx.x] = fmaxf(rm[threadIdx.x], rm[threadIdx.x + off]);
      rs[threadIdx.x] += rs[threadIdx.x + off];
    }
    __syncthreads();
  }
  if (threadIdx.x == 0) { mx[b * 512 + c] = rm[0]; av[b * 512 + c] = rs[0] / (float)N_; }
}

// ================= CBAM channel MLPs -> svec = sigmoid(wmax+wavg) =================
__global__ __launch_bounds__(256) void k_mlp(const float* __restrict__ mx,
    const float* __restrict__ av,
    const float* __restrict__ w1m, const float* __restrict__ b1m,
    const float* __restrict__ w2m, const float* __restrict__ b2m,
    const float* __restrict__ w1a, const float* __restrict__ b1a,
    const float* __restrict__ w2a, const float* __restrict__ b2a,
    float* __restrict__ svec) {
  __shared__ float hm[4][256], ha[4][256];
  int j = threadIdx.x;
  for (int b = 0; b < 4; b++) {
    float am = b1m[j], aa = b1a[j];
    for (int i = 0; i < 512; i++) {
      am += mx[b * 512 + i] * w1m[j * 512 + i];
      aa += av[b * 512 + i] * w1a[j * 512 + i];
    }
    hm[b][j] = fmaxf(am, 0.f);
    ha[b][j] = fmaxf(aa, 0.f);
  }
  __syncthreads();
  for (int o = threadIdx.x; o < 512; o += 256) {
    for (int b = 0; b < 4; b++) {
      float sm = b2m[o], sa = b2a[o];
      for (int jj = 0; jj < 256; jj++) {
        sm += hm[b][jj] * w2m[o * 256 + jj];
        sa += ha[b][jj] * w2a[o * 256 + jj];
      }
      float wm = 1.f / (1.f + __expf(-sm));
      float wa = 1.f / (1.f + __expf(-sa));
      svec[b * 512 + o] = 1.f / (1.f + __expf(-(wm + wa)));
    }
  }
}

// ================= spatial-attn input: per-pixel max/mean over 512 scaled channels ======
__global__ __launch_bounds__(256) void k_cat(const bf16* __restrict__ loc,
    const float* __restrict__ svec, float* __restrict__ catmax, float* __restrict__ catmean) {
  int b = blockIdx.y;
  int n = blockIdx.x * 256 + threadIdx.x;
  const bf16* lb = loc + (size_t)b * 512 * N_;
  const float* sv = svec + b * 512;
  float m = -1e30f, s = 0.f;
  for (int c = 0; c < 512; c++) {
    float v = toF(lb[(size_t)c * N_ + n]) * sv[c];
    m = fmaxf(m, v); s += v;
  }
  catmax[b * N_ + n] = m;
  catmean[b * N_ + n] = s * (1.f / 512.f);
}

// ================= spatial attention 7x7 conv -> sigmoid =================
__global__ __launch_bounds__(256) void k_sa(const float* __restrict__ catmax,
    const float* __restrict__ catmean, const float* __restrict__ saw,
    const float* __restrict__ sab, float* __restrict__ samap) {
  int b = blockIdx.y;
  int n = blockIdx.x * 256 + threadIdx.x;
  int y = n >> 7, x = n & 127;
  float acc = sab[0];
  for (int u = 0; u < 7; u++) {
    int yy = y + u - 3;
    if (yy < 0 || yy >= H_) continue;
    for (int v = 0; v < 7; v++) {
      int xx = x + v - 3;
      if (xx < 0 || xx >= W_) continue;
      int nn = b * N_ + yy * W_ + xx;
      acc += catmax[nn] * saw[u * 7 + v] + catmean[nn] * saw[49 + u * 7 + v];
    }
  }
  samap[b * N_ + n] = 1.f / (1.f + __expf(-acc));
}

// ================= scale loc in place by svec[c] * samap[n] =================
__global__ __launch_bounds__(256) void k_locscale(bf16* __restrict__ loc,
    const float* __restrict__ svec, const float* __restrict__ samap) {
  int b = blockIdx.z, c = blockIdx.y;
  int n = blockIdx.x * 256 + threadIdx.x;
  size_t o = ((size_t)b * 512 + c) * N_ + n;
  loc[o] = __float2bfloat16(toF(loc[o]) * svec[b * 512 + c] * samap[b * N_ + n]);
}

// ================= directional avg pools (reflect-extended) + local add =================
__global__ __launch_bounds__(256) void k_out1(const bf16* __restrict__ img,
    const bf16* __restrict__ locout, bf16* __restrict__ out1) {
  int b = blockIdx.z, c = blockIdx.y;
  int n = blockIdx.x * 256 + threadIdx.x;
  int y = n >> 7, x = n & 127;
  const bf16* p = img + ((size_t)b * 256 + c) * N_;
  float sv = 0.f, sh = 0.f;
#pragma unroll
  for (int t = -3; t <= 4; t++) {
    int r = y + t;
    if (r >= 0 && r <= 128) { int rr = (r == 128) ? 126 : r; sv += toF(p[rr * W_ + x]); }
    int s2 = x + t;
    if (s2 >= 0 && s2 <= 128) { int ss = (s2 == 128) ? 126 : s2; sh += toF(p[y * W_ + ss]); }
  }
  size_t o = ((size_t)b * 256 + c) * N_ + n;
  out1[o] = __float2bfloat16(0.125f * (sv + sh) + toF(locout[o]));
}

// ================= depthwise 8x8 (reflect+zero pad) + BN =================
__global__ __launch_bounds__(256) void k_dw(const bf16* __restrict__ out1,
    const float* __restrict__ dww, const float* __restrict__ bng,
    const float* __restrict__ bnb, bf16* __restrict__ dwo) {
  int b = blockIdx.z, c = blockIdx.y;
  int n = blockIdx.x * 256 + threadIdx.x;
  int y = n >> 7, x = n & 127;
  const bf16* p = out1 + ((size_t)b * 256 + c) * N_;
  const float* w = dww + c * 64;
  float acc = 0.f;
  for (int u = 0; u < 8; u++) {
    int r = y + u - 3;
    if (r < 0 || r > 128) continue;
    int rr = (r == 128) ? 126 : r;
    for (int v = 0; v < 8; v++) {
      int s2 = x + v - 3;
      if (s2 < 0 || s2 > 128) continue;
      int ss = (s2 == 128) ? 126 : s2;
      acc += toF(p[rr * W_ + ss]) * w[u * 8 + v];
    }
  }
  float g = bng[c] * rsqrtf(1.0f + 1e-5f);
  dwo[((size_t)b * 256 + c) * N_ + n] = __float2bfloat16(acc * g + bnb[c]);
}

// =========================== launcher ===========================
extern "C" void kernel_launch(void* const* d_in, const int* in_sizes, int n_in,
                              void* d_out, int out_size, void* d_ws, size_t ws_size,
                              hipStream_t stream) {
  const float* x        = (const float*)d_in[0];
  const float* qkv_w    = (const float*)d_in[1];
  const float* ld1_w    = (const float*)d_in[2];
  const float* ld2_w    = (const float*)d_in[3];
  const float* camax_w1 = (const float*)d_in[4];
  const float* camax_b1 = (const float*)d_in[5];
  const float* camax_w2 = (const float*)d_in[6];
  const float* camax_b2 = (const float*)d_in[7];
  const float* caavg_w1 = (const float*)d_in[8];
  const float* caavg_b1 = (const float*)d_in[9];
  const float* caavg_w2 = (const float*)d_in[10];
  const float* caavg_b2 = (const float*)d_in[11];
  const float* sa_w     = (const float*)d_in[12];
  const float* sa_b     = (const float*)d_in[13];
  const float* f3_w     = (const float*)d_in[14];
  const float* f3_b     = (const float*)d_in[15];
  const float* f5_w     = (const float*)d_in[16];
  const float* f5_b     = (const float*)d_in[17];
  const float* f7_w     = (const float*)d_in[18];
  const float* f7_b     = (const float*)d_in[19];
  const float* rel_tab  = (const float*)d_in[20];
  const float* dw_w     = (const float*)d_in[21];
  const float* bn_g     = (const float*)d_in[22];
  const float* bn_b     = (const float*)d_in[23];
  const float* pw_w     = (const float*)d_in[24];
  float* out = (float*)d_out;

  // ---- arena (byte offsets), peak ~135.2 MiB ----
  char* wsb = (char*)d_ws;
  bf16* qkvb   = (bf16*)(wsb);                    // [4][768][16384] bf16 = 96 MiB
  bf16* dfb    = (bf16*)(wsb + 100663296);        // [4][256][16384] bf16 = 32 MiB (df, then img in-place)
  bf16* locb   = (bf16*)(wsb);                    // [4][512][16384] bf16 = 64 MiB (qkv dead)
  bf16* locout = (bf16*)(wsb + 67108864);         // [4][256][16384] bf16 = 32 MiB
  bf16* out1   = (bf16*)(wsb);                    // 32 MiB (locb dead)
  bf16* dwo    = (bf16*)(wsb + 33554432);         // 32 MiB
  float* small = (float*)(wsb + 134217728);       // ~0.92 MiB of f32 scratch
  float* pools   = small;                         // [4][256][36]
  float* mx      = small + 36864;                 // [4][512]
  float* av      = small + 38912;                 // [4][512]
  float* svec    = small + 40960;                 // [4][512]
  float* catmax  = small + 43008;                 // [4][16384]
  float* catmean = small + 108544;                // [4][16384]
  float* samap   = small + 174080;                // [4][16384]

  dim3 blk(256);
  // attention / filter branch
  gemm1x1<float, bf16><<<dim3(256, 12, 4), blk, 0, stream>>>(qkv_w, x, qkvb, 768, 256);
  k_lp_pool<<<dim3(36, 256, 4), blk, 0, stream>>>(qkvb, pools);
  k_dffuse<<<dim3(64, 256, 4), blk, 0, stream>>>(qkvb, pools, f3_w, f3_b, f5_w, f5_b,
                                                 f7_w, f7_b, dfb);
  k_attn<<<dim3(256, 8, 4), blk, 0, stream>>>(qkvb, dfb, rel_tab);
  // local (CBAM) branch — runs after attention so it can reuse the qkv region
  gemm1x1<float, bf16><<<dim3(256, 8, 4), blk, 0, stream>>>(ld1_w, x, locb, 512, 256);
  k_chstats<<<dim3(512, 4), blk, 0, stream>>>(locb, mx, av);
  k_mlp<<<dim3(1), blk, 0, stream>>>(mx, av, camax_w1, camax_b1, camax_w2, camax_b2,
                                     caavg_w1, caavg_b1, caavg_w2, caavg_b2, svec);
  k_cat<<<dim3(64, 4), blk, 0, stream>>>(locb, svec, catmax, catmean);
  k_sa<<<dim3(64, 4), blk, 0, stream>>>(catmax, catmean, sa_w, sa_b, samap);
  k_locscale<<<dim3(64, 512, 4), blk, 0, stream>>>(locb, svec, samap);
  gemm1x1<bf16, bf16><<<dim3(256, 4, 4), blk, 0, stream>>>(ld2_w, locb, locout, 256, 512);
  // merge + projection
  k_out1<<<dim3(64, 256, 4), blk, 0, stream>>>(dfb, locout, out1);
  k_dw<<<dim3(64, 256, 4), blk, 0, stream>>>(out1, dw_w, bn_g, bn_b, dwo);
  gemm1x1<bf16, float><<<dim3(256, 4, 4), blk, 0, stream>>>(pw_w, dwo, out, 256, 256);
}

// Round 4
// 1620.588 us; speedup vs baseline: 1.5445x; 1.5445x over previous
//
#include <hip/hip_runtime.h>
#include <hip/hip_bf16.h>
#include <math.h>

#define B_ 4
#define H_ 128
#define W_ 128
#define N_ 16384

using bf16 = __hip_bfloat16;
typedef short short8 __attribute__((ext_vector_type(8)));
typedef float f32x4 __attribute__((ext_vector_type(4)));

__device__ __forceinline__ float toF(float v) { return v; }
__device__ __forceinline__ float toF(bf16 v) { return __bfloat162float(v); }
__device__ __forceinline__ void storeF(float* p, float v) { *p = v; }
__device__ __forceinline__ void storeF(bf16* p, float v) { *p = __float2bfloat16(v); }

__device__ __forceinline__ unsigned short f2bf(float f) {
  unsigned u = __builtin_bit_cast(unsigned, f);
  unsigned r = (u + 0x7FFFu + ((u >> 16) & 1u)) >> 16;
  return (unsigned short)r;
}
__device__ __forceinline__ short rawbf(float v) { return (short)f2bf(v); }
__device__ __forceinline__ short rawbf(bf16 v) { return __builtin_bit_cast(short, v); }

// load 8 contiguous bf16 as raw shorts
__device__ __forceinline__ short8 ld8(const bf16* p) { return *(const short8*)p; }

// ===== MFMA GEMM: Y[b][oc][n] = sum_ic W[oc][ic] * X[b][ic][n] =====
// A = W (bf16 [OC][IC]); B = X ([IC][N_], f32 or bf16).
// BM=BN=128, BK=64, 4 waves (2x2), each wave 64x64 via 4x4 frags of 16x16x32.
// BOTH tiles in LDS as [row][64 k] bf16 with (kgroup ^ (row&7)) XOR swizzle;
// A rows = oc (k-contiguous in global, vector load), B rows = n (transposed on
// the global-load side: 8 coalesced stride-N_ scalar loads per thread).
// Fragments for both operands: one ds_read_b128 of 8 k-contiguous bf16.
template <typename TX, typename TY>
__global__ __launch_bounds__(256) void gemm_mfma(
    const bf16* __restrict__ Wb, const TX* __restrict__ X, TY* __restrict__ Y, int IC) {
  __shared__ short smA[8192];  // 16 KB  [128 oc][64 k] swizzled
  __shared__ short smB[8192];  // 16 KB  [128 n ][64 k] swizzled
  int tid = threadIdx.x;
  int lane = tid & 63, w = tid >> 6;
  int wm = w >> 1, wn = w & 1;
  int n0 = blockIdx.x * 128, oc0 = blockIdx.y * 128, b = blockIdx.z;
  const TX* Xb = X + (size_t)b * IC * N_;
  TY* Yb = Y + (size_t)b * (gridDim.y * 128) * N_;
  f32x4 acc[4][4] = {};
  int nB = tid & 127;          // B row this thread stages (same for all i)
  int gB0 = tid >> 7;          // 0 or 1

  for (int k0 = 0; k0 < IC; k0 += 64) {
    // ---- stage A,B tiles into registers (global) ----
    short8 areg[4], breg[4];
#pragma unroll
    for (int i = 0; i < 4; i++) {
      int q = i * 256 + tid;             // A chunk: row=q>>3, kgroup g=q&7
      int rowA = q >> 3, gA = q & 7;
      areg[i] = ld8(Wb + (size_t)(oc0 + rowA) * IC + k0 + gA * 8);
      int gB = i * 2 + gB0;              // B: k-group, row nB
      const TX* src = Xb + (size_t)(k0 + gB * 8) * N_ + n0 + nB;
      short8 v;
#pragma unroll
      for (int j = 0; j < 8; j++) v[j] = rawbf(src[(size_t)j * N_]);
      breg[i] = v;
    }
    __syncthreads();  // prior iteration's fragment reads complete
#pragma unroll
    for (int i = 0; i < 4; i++) {
      int q = i * 256 + tid;
      int rowA = q >> 3, gA = q & 7;
      *(short8*)&smA[rowA * 64 + ((gA ^ (rowA & 7)) * 8)] = areg[i];
      int gB = i * 2 + gB0;
      *(short8*)&smB[nB * 64 + ((gB ^ (nB & 7)) * 8)] = breg[i];
    }
    __syncthreads();
    // ---- MFMA over the two 32-wide k-steps ----
#pragma unroll
    for (int ks = 0; ks < 2; ks++) {
      int gk = ks * 4 + (lane >> 4);
      short8 af[4], bfr[4];
#pragma unroll
      for (int mf = 0; mf < 4; mf++) {
        int row = wm * 64 + mf * 16 + (lane & 15);
        af[mf] = *(const short8*)&smA[row * 64 + ((gk ^ (row & 7)) * 8)];
      }
#pragma unroll
      for (int nf = 0; nf < 4; nf++) {
        int nr = wn * 64 + nf * 16 + (lane & 15);
        bfr[nf] = *(const short8*)&smB[nr * 64 + ((gk ^ (nr & 7)) * 8)];
      }
#pragma unroll
      for (int nf = 0; nf < 4; nf++)
#pragma unroll
        for (int mf = 0; mf < 4; mf++)
          acc[mf][nf] = __builtin_amdgcn_mfma_f32_16x16x32_bf16(af[mf], bfr[nf], acc[mf][nf], 0, 0, 0);
    }
    __syncthreads();
  }
  // ---- store: D row = (lane>>4)*4 + j (oc), col = lane&15 (n) ----
#pragma unroll
  for (int mf = 0; mf < 4; mf++)
#pragma unroll
    for (int nf = 0; nf < 4; nf++) {
      int ocr = oc0 + wm * 64 + mf * 16 + ((lane >> 4) << 2);
      int nc = n0 + wn * 64 + nf * 16 + (lane & 15);
#pragma unroll
      for (int j = 0; j < 4; j++)
        storeF(&Yb[(size_t)(ocr + j) * N_ + nc], acc[mf][nf][j]);
    }
}

// ================= weight f32 -> bf16 =================
__global__ __launch_bounds__(256) void k_cvt(const float* __restrict__ s,
                                             bf16* __restrict__ d, int n) {
  int i = blockIdx.x * 256 + threadIdx.x;
  if (i < n) d[i] = __float2bfloat16(s[i]);
}

// ================= LP: adaptive avg pool per region (from bf16 qkv v-channels) ==========
__global__ __launch_bounds__(256) void k_lp_pool(const bf16* __restrict__ qkv,
                                                 float* __restrict__ pools) {
  int b = blockIdx.z, cc = blockIdx.y, r = blockIdx.x;  // r < 36
  int g = cc >> 6;
  const int S[4] = {1, 2, 3, 6};
  int s = S[g];
  if (r >= s * s) return;
  int i = r / s, j = r % s;
  int h0 = (i * H_) / s, h1 = ((i + 1) * H_ + s - 1) / s;
  int w0 = (j * W_) / s, w1 = ((j + 1) * W_ + s - 1) / s;
  int vch = 512 + (cc & 31) * 8 + (cc >> 5);
  const bf16* src = qkv + ((size_t)b * 768 + vch) * N_;
  int wlen = w1 - w0;
  int cnt = (h1 - h0) * wlen;
  float sum = 0.f;
  for (int idx = threadIdx.x; idx < cnt; idx += 256) {
    int yy = h0 + idx / wlen;
    int xx = w0 + idx % wlen;
    sum += toF(src[yy * W_ + xx]);
  }
  __shared__ float red[256];
  red[threadIdx.x] = sum;
  __syncthreads();
  for (int off = 128; off > 0; off >>= 1) {
    if (threadIdx.x < off) red[threadIdx.x] += red[threadIdx.x + off];
    __syncthreads();
  }
  if (threadIdx.x == 0) pools[((size_t)b * 256 + cc) * 36 + r] = red[0] / (float)cnt;
}

// ======== fused: HP depthwise conv + LP bilinear-up(relu) + df = q*HP + LP ========
__global__ __launch_bounds__(256) void k_dffuse(const bf16* __restrict__ qkv,
    const float* __restrict__ pools,
    const float* __restrict__ f3w, const float* __restrict__ f3b,
    const float* __restrict__ f5w, const float* __restrict__ f5b,
    const float* __restrict__ f7w, const float* __restrict__ f7b,
    bf16* __restrict__ df) {
  int b = blockIdx.z, cc = blockIdx.y;
  int n = blockIdx.x * 256 + threadIdx.x;
  int y = n >> 7, x = n & 127;
  int vch = 512 + (cc & 31) * 8 + (cc >> 5);   // v in (d,h) channel decomposition
  const bf16* src = qkv + ((size_t)b * 768 + vch) * N_;
  int ksz; const float* wp; float bias;
  if (cc < 64)       { ksz = 3; wp = f3w + cc * 9;          bias = f3b[cc]; }
  else if (cc < 160) { ksz = 5; wp = f5w + (cc - 64) * 25;  bias = f5b[cc - 64]; }
  else               { ksz = 7; wp = f7w + (cc - 160) * 49; bias = f7b[cc - 160]; }
  int r = ksz >> 1;
  float hp = bias;
  for (int u = 0; u < ksz; u++) {
    int yy = y + u - r;
    if (yy < 0 || yy >= H_) continue;
    for (int v = 0; v < ksz; v++) {
      int xx = x + v - r;
      if (xx < 0 || xx >= W_) continue;
      hp += toF(src[yy * W_ + xx]) * wp[u * ksz + v];
    }
  }
  const int S[4] = {1, 2, 3, 6};
  int s = S[cc >> 6];
  const float* pl = pools + ((size_t)b * 256 + cc) * 36;
  float fy = (y + 0.5f) * s * (1.0f / 128.f) - 0.5f;
  float fx = (x + 0.5f) * s * (1.0f / 128.f) - 0.5f;
  int i0 = (int)floorf(fy); float ty = fy - i0;
  int j0 = (int)floorf(fx); float tx = fx - j0;
  int i1 = i0 + 1, j1 = j0 + 1;
  i0 = min(max(i0, 0), s - 1); i1 = min(max(i1, 0), s - 1);
  j0 = min(max(j0, 0), s - 1); j1 = min(max(j1, 0), s - 1);
  float v00 = pl[i0 * s + j0], v01 = pl[i0 * s + j1];
  float v10 = pl[i1 * s + j0], v11 = pl[i1 * s + j1];
  float lp = (1.f - ty) * ((1.f - tx) * v00 + tx * v01) + ty * ((1.f - tx) * v10 + tx * v11);
  lp = fmaxf(lp, 0.f);
  int qch = (cc & 31) * 8 + (cc >> 5);   // q in (d,h) decomposition
  float q = toF(qkv[((size_t)b * 768 + qch) * N_ + n]);
  df[((size_t)b * 256 + cc) * N_ + n] = __float2bfloat16(q * hp + lp);
}

// ======== window attention (8x8, rel bias, softmax, apply to df) — img in-place over df ==
__global__ __launch_bounds__(256) void k_attn(const bf16* __restrict__ qkv,
    bf16* __restrict__ df, const float* __restrict__ rel) {
  int b = blockIdx.z, head = blockIdx.y, win = blockIdx.x;
  int wh = win >> 4, wc = win & 15;
  __shared__ float qs[64][33], ks[64][33], ds[64][33];
  __shared__ float pm[64][65];
  __shared__ float bias_s[225];
  int tid = threadIdx.x;
  for (int i = tid; i < 225; i += 256) bias_s[i] = rel[i * 8 + head];
  int dc = tid >> 3, c2 = tid & 7;
  const bf16* qsrc = qkv + ((size_t)b * 768 + head * 32 + dc) * N_;  // (h,d) decomp
  const bf16* ksrc = qkv + ((size_t)b * 768 + 256 + head * 32 + dc) * N_;
  const bf16* dsrc = df + ((size_t)b * 256 + head * 32 + dc) * N_;
#pragma unroll
  for (int r = 0; r < 8; r++) {
    int n = (wh * 8 + r) * W_ + wc * 8 + c2;
    int l = r * 8 + c2;
    qs[l][dc] = toF(qsrc[n]);
    ks[l][dc] = toF(ksrc[n]);
    ds[l][dc] = toF(dsrc[n]);
  }
  __syncthreads();
  int l = tid >> 2, mg = tid & 3;
  int r1 = l >> 3, c1 = l & 7;
  const float scale = 0.17677669529663687f;  // 32^-0.5
  float vals[16];
  float mymax = -1e30f;
#pragma unroll
  for (int mi = 0; mi < 16; mi++) {
    int m = mg * 16 + mi;
    float a = 0.f;
#pragma unroll
    for (int kk = 0; kk < 32; kk++) a += qs[l][kk] * ks[m][kk];
    int r2 = m >> 3, c2m = m & 7;
    a = a * scale + bias_s[(r1 - r2 + 7) * 15 + (c1 - c2m + 7)];
    vals[mi] = a;
    mymax = fmaxf(mymax, a);
  }
  mymax = fmaxf(mymax, __shfl_xor(mymax, 1));
  mymax = fmaxf(mymax, __shfl_xor(mymax, 2));
  float mysum = 0.f;
#pragma unroll
  for (int mi = 0; mi < 16; mi++) { vals[mi] = __expf(vals[mi] - mymax); mysum += vals[mi]; }
  mysum += __shfl_xor(mysum, 1);
  mysum += __shfl_xor(mysum, 2);
  float inv = 1.0f / mysum;
#pragma unroll
  for (int mi = 0; mi < 16; mi++) pm[l][mg * 16 + mi] = vals[mi] * inv;
  __syncthreads();
  int dg = tid & 3;
  float acc[8] = {};
  for (int m = 0; m < 64; m++) {
    float p = pm[l][m];
#pragma unroll
    for (int q2 = 0; q2 < 8; q2++) acc[q2] += p * ds[m][dg * 8 + q2];
  }
  int n = (wh * 8 + r1) * W_ + wc * 8 + c1;
#pragma unroll
  for (int q2 = 0; q2 < 8; q2++)
    df[((size_t)b * 256 + head * 32 + dg * 8 + q2) * N_ + n] = __float2bfloat16(acc[q2]);
}

// ================= CBAM: per-channel max/mean over pixels =================
__global__ __launch_bounds__(256) void k_chstats(const bf16* __restrict__ loc,
    float* __restrict__ mx, float* __restrict__ av) {
  int c = blockIdx.x, b = blockIdx.y;
  const bf16* p = loc + ((size_t)b * 512 + c) * N_;
  float m = -1e30f, s = 0.f;
  for (int i = threadIdx.x; i < N_; i += 256) { float v = toF(p[i]); m = fmaxf(m, v); s += v; }
  __shared__ float rm[256], rs[256];
  rm[threadIdx.x] = m; rs[threadIdx.x] = s;
  __syncthreads();
  for (int off = 128; off > 0; off >>= 1) {
    if (threadIdx.x < off) {
      rm[threadIdx.x] = fmaxf(rm[threadIdx.x], rm[threadIdx.x + off]);
      rs[threadIdx.x] += rs[threadIdx.x + off];
    }
    __syncthreads();
  }
  if (threadIdx.x == 0) { mx[b * 512 + c] = rm[0]; av[b * 512 + c] = rs[0] / (float)N_; }
}

// ================= CBAM channel MLPs -> svec = sigmoid(wmax+wavg) =================
__global__ __launch_bounds__(256) void k_mlp(const float* __restrict__ mx,
    const float* __restrict__ av,
    const float* __restrict__ w1m, const float* __restrict__ b1m,
    const float* __restrict__ w2m, const float* __restrict__ b2m,
    const float* __restrict__ w1a, const float* __restrict__ b1a,
    const float* __restrict__ w2a, const float* __restrict__ b2a,
    float* __restrict__ svec) {
  __shared__ float hm[4][256], ha[4][256];
  int j = threadIdx.x;
  for (int b = 0; b < 4; b++) {
    float am = b1m[j], aa = b1a[j];
    for (int i = 0; i < 512; i++) {
      am += mx[b * 512 + i] * w1m[j * 512 + i];
      aa += av[b * 512 + i] * w1a[j * 512 + i];
    }
    hm[b][j] = fmaxf(am, 0.f);
    ha[b][j] = fmaxf(aa, 0.f);
  }
  __syncthreads();
  for (int o = threadIdx.x; o < 512; o += 256) {
    for (int b = 0; b < 4; b++) {
      float sm = b2m[o], sa = b2a[o];
      for (int jj = 0; jj < 256; jj++) {
        sm += hm[b][jj] * w2m[o * 256 + jj];
        sa += ha[b][jj] * w2a[o * 256 + jj];
      }
      float wm = 1.f / (1.f + __expf(-sm));
      float wa = 1.f / (1.f + __expf(-sa));
      svec[b * 512 + o] = 1.f / (1.f + __expf(-(wm + wa)));
    }
  }
}

// ================= spatial-attn input: per-pixel max/mean over 512 scaled channels ======
__global__ __launch_bounds__(256) void k_cat(const bf16* __restrict__ loc,
    const float* __restrict__ svec, float* __restrict__ catmax, float* __restrict__ catmean) {
  int b = blockIdx.y;
  int n = blockIdx.x * 256 + threadIdx.x;
  const bf16* lb = loc + (size_t)b * 512 * N_;
  const float* sv = svec + b * 512;
  float m = -1e30f, s = 0.f;
  for (int c = 0; c < 512; c++) {
    float v = toF(lb[(size_t)c * N_ + n]) * sv[c];
    m = fmaxf(m, v); s += v;
  }
  catmax[b * N_ + n] = m;
  catmean[b * N_ + n] = s * (1.f / 512.f);
}

// ================= spatial attention 7x7 conv -> sigmoid =================
__global__ __launch_bounds__(256) void k_sa(const float* __restrict__ catmax,
    const float* __restrict__ catmean, const float* __restrict__ saw,
    const float* __restrict__ sab, float* __restrict__ samap) {
  int b = blockIdx.y;
  int n = blockIdx.x * 256 + threadIdx.x;
  int y = n >> 7, x = n & 127;
  float acc = sab[0];
  for (int u = 0; u < 7; u++) {
    int yy = y + u - 3;
    if (yy < 0 || yy >= H_) continue;
    for (int v = 0; v < 7; v++) {
      int xx = x + v - 3;
      if (xx < 0 || xx >= W_) continue;
      int nn = b * N_ + yy * W_ + xx;
      acc += catmax[nn] * saw[u * 7 + v] + catmean[nn] * saw[49 + u * 7 + v];
    }
  }
  samap[b * N_ + n] = 1.f / (1.f + __expf(-acc));
}

// ================= scale loc in place by svec[c] * samap[n] =================
__global__ __launch_bounds__(256) void k_locscale(bf16* __restrict__ loc,
    const float* __restrict__ svec, const float* __restrict__ samap) {
  int b = blockIdx.z, c = blockIdx.y;
  int n = blockIdx.x * 256 + threadIdx.x;
  size_t o = ((size_t)b * 512 + c) * N_ + n;
  loc[o] = __float2bfloat16(toF(loc[o]) * svec[b * 512 + c] * samap[b * N_ + n]);
}

// ================= directional avg pools (reflect-extended) + local add =================
__global__ __launch_bounds__(256) void k_out1(const bf16* __restrict__ img,
    const bf16* __restrict__ locout, bf16* __restrict__ out1) {
  int b = blockIdx.z, c = blockIdx.y;
  int n = blockIdx.x * 256 + threadIdx.x;
  int y = n >> 7, x = n & 127;
  const bf16* p = img + ((size_t)b * 256 + c) * N_;
  float sv = 0.f, sh = 0.f;
#pragma unroll
  for (int t = -3; t <= 4; t++) {
    int r = y + t;
    if (r >= 0 && r <= 128) { int rr = (r == 128) ? 126 : r; sv += toF(p[rr * W_ + x]); }
    int s2 = x + t;
    if (s2 >= 0 && s2 <= 128) { int ss = (s2 == 128) ? 126 : s2; sh += toF(p[y * W_ + ss]); }
  }
  size_t o = ((size_t)b * 256 + c) * N_ + n;
  out1[o] = __float2bfloat16(0.125f * (sv + sh) + toF(locout[o]));
}

// ================= depthwise 8x8 (reflect+zero pad) + BN =================
__global__ __launch_bounds__(256) void k_dw(const bf16* __restrict__ out1,
    const float* __restrict__ dww, const float* __restrict__ bng,
    const float* __restrict__ bnb, bf16* __restrict__ dwo) {
  int b = blockIdx.z, c = blockIdx.y;
  int n = blockIdx.x * 256 + threadIdx.x;
  int y = n >> 7, x = n & 127;
  const bf16* p = out1 + ((size_t)b * 256 + c) * N_;
  const float* w = dww + c * 64;
  float acc = 0.f;
  for (int u = 0; u < 8; u++) {
    int r = y + u - 3;
    if (r < 0 || r > 128) continue;
    int rr = (r == 128) ? 126 : r;
    for (int v = 0; v < 8; v++) {
      int s2 = x + v - 3;
      if (s2 < 0 || s2 > 128) continue;
      int ss = (s2 == 128) ? 126 : s2;
      acc += toF(p[rr * W_ + ss]) * w[u * 8 + v];
    }
  }
  float g = bng[c] * rsqrtf(1.0f + 1e-5f);
  dwo[((size_t)b * 256 + c) * N_ + n] = __float2bfloat16(acc * g + bnb[c]);
}

// =========================== launcher ===========================
extern "C" void kernel_launch(void* const* d_in, const int* in_sizes, int n_in,
                              void* d_out, int out_size, void* d_ws, size_t ws_size,
                              hipStream_t stream) {
  const float* x        = (const float*)d_in[0];
  const float* qkv_w    = (const float*)d_in[1];
  const float* ld1_w    = (const float*)d_in[2];
  const float* ld2_w    = (const float*)d_in[3];
  const float* camax_w1 = (const float*)d_in[4];
  const float* camax_b1 = (const float*)d_in[5];
  const float* camax_w2 = (const float*)d_in[6];
  const float* camax_b2 = (const float*)d_in[7];
  const float* caavg_w1 = (const float*)d_in[8];
  const float* caavg_b1 = (const float*)d_in[9];
  const float* caavg_w2 = (const float*)d_in[10];
  const float* caavg_b2 = (const float*)d_in[11];
  const float* sa_w     = (const float*)d_in[12];
  const float* sa_b     = (const float*)d_in[13];
  const float* f3_w     = (const float*)d_in[14];
  const float* f3_b     = (const float*)d_in[15];
  const float* f5_w     = (const float*)d_in[16];
  const float* f5_b     = (const float*)d_in[17];
  const float* f7_w     = (const float*)d_in[18];
  const float* f7_b     = (const float*)d_in[19];
  const float* rel_tab  = (const float*)d_in[20];
  const float* dw_w     = (const float*)d_in[21];
  const float* bn_g     = (const float*)d_in[22];
  const float* bn_b     = (const float*)d_in[23];
  const float* pw_w     = (const float*)d_in[24];
  float* out = (float*)d_out;

  // ---- arena (byte offsets), peak ~130 MiB ----
  char* wsb = (char*)d_ws;
  bf16* qkvb   = (bf16*)(wsb);                    // [4][768][16384] bf16 = 96 MiB
  bf16* dfb    = (bf16*)(wsb + 100663296);        // [4][256][16384] bf16 = 32 MiB (df -> img in-place)
  bf16* locb   = (bf16*)(wsb);                    // [4][512][16384] bf16 = 64 MiB (qkv dead)
  bf16* locout = (bf16*)(wsb + 67108864);         // [4][256][16384] bf16 = 32 MiB
  bf16* out1   = (bf16*)(wsb);                    // 32 MiB (locb dead)
  bf16* dwo    = (bf16*)(wsb + 33554432);         // 32 MiB
  float* small = (float*)(wsb + 134217728);       // small f32 scratch
  float* pools   = small;                         // [4][256][36]
  float* mx      = small + 36864;                 // [4][512]
  float* av      = small + 38912;                 // [4][512]
  float* svec    = small + 40960;                 // [4][512]
  float* catmax  = small + 43008;                 // [4][16384]
  float* catmean = small + 108544;                // [4][16384]
  float* samap   = small + 174080;                // [4][16384]
  // bf16 weights after the f32 small area (byte 135176192)
  bf16* wq  = (bf16*)(wsb + 135176192);           // 768*256
  bf16* wl1 = wq  + 196608;                       // 512*256
  bf16* wl2 = wl1 + 131072;                       // 256*512
  bf16* wpw = wl2 + 131072;                       // 256*256

  dim3 blk(256);
  // weight conversion
  k_cvt<<<dim3(768), blk, 0, stream>>>(qkv_w, wq, 196608);
  k_cvt<<<dim3(512), blk, 0, stream>>>(ld1_w, wl1, 131072);
  k_cvt<<<dim3(512), blk, 0, stream>>>(ld2_w, wl2, 131072);
  k_cvt<<<dim3(256), blk, 0, stream>>>(pw_w, wpw, 65536);

  // attention / filter branch
  gemm_mfma<float, bf16><<<dim3(128, 6, 4), blk, 0, stream>>>(wq, x, qkvb, 256);
  k_lp_pool<<<dim3(36, 256, 4), blk, 0, stream>>>(qkvb, pools);
  k_dffuse<<<dim3(64, 256, 4), blk, 0, stream>>>(qkvb, pools, f3_w, f3_b, f5_w, f5_b,
                                                 f7_w, f7_b, dfb);
  k_attn<<<dim3(256, 8, 4), blk, 0, stream>>>(qkvb, dfb, rel_tab);
  // local (CBAM) branch — runs after attention so it can reuse the qkv region
  gemm_mfma<float, bf16><<<dim3(128, 4, 4), blk, 0, stream>>>(wl1, x, locb, 256);
  k_chstats<<<dim3(512, 4), blk, 0, stream>>>(locb, mx, av);
  k_mlp<<<dim3(1), blk, 0, stream>>>(mx, av, camax_w1, camax_b1, camax_w2, camax_b2,
                                     caavg_w1, caavg_b1, caavg_w2, caavg_b2, svec);
  k_cat<<<dim3(64, 4), blk, 0, stream>>>(locb, svec, catmax, catmean);
  k_sa<<<dim3(64, 4), blk, 0, stream>>>(catmax, catmean, sa_w, sa_b, samap);
  k_locscale<<<dim3(64, 512, 4), blk, 0, stream>>>(locb, svec, samap);
  gemm_mfma<bf16, bf16><<<dim3(128, 2, 4), blk, 0, stream>>>(wl2, locb, locout, 512);
  // merge + projection
  k_out1<<<dim3(64, 256, 4), blk, 0, stream>>>(dfb, locout, out1);
  k_dw<<<dim3(64, 256, 4), blk, 0, stream>>>(out1, dw_w, bn_g, bn_b, dwo);
  gemm_mfma<bf16, float><<<dim3(128, 2, 4), blk, 0, stream>>>(wpw, dwo, out, 256);
}

// Round 5
// 1209.311 us; speedup vs baseline: 2.0698x; 1.3401x over previous
//
#include <hip/hip_runtime.h>
#include <hip/hip_bf16.h>
#include <math.h>

#define B_ 4
#define H_ 128
#define W_ 128
#define N_ 16384

using bf16 = __hip_bfloat16;
typedef short short8 __attribute__((ext_vector_type(8)));
typedef short s16x4 __attribute__((ext_vector_type(4)));
typedef float f32x4 __attribute__((ext_vector_type(4)));

__device__ __forceinline__ float toF(float v) { return v; }
__device__ __forceinline__ float toF(bf16 v) { return __bfloat162float(v); }
__device__ __forceinline__ void storeF(float* p, float v) { *p = v; }
__device__ __forceinline__ void storeF(bf16* p, float v) { *p = __float2bfloat16(v); }

__device__ __forceinline__ unsigned short f2bf(float f) {
  unsigned u = __builtin_bit_cast(unsigned, f);
  unsigned r = (u + 0x7FFFu + ((u >> 16) & 1u)) >> 16;
  return (unsigned short)r;
}
__device__ __forceinline__ short rawbf(float v) { return (short)f2bf(v); }
__device__ __forceinline__ short rawbf(bf16 v) { return __builtin_bit_cast(short, v); }
__device__ __forceinline__ float bfs2f(short s) {
  return __builtin_bit_cast(float, ((unsigned)(unsigned short)s) << 16);
}

// load 8 contiguous bf16 as raw shorts
__device__ __forceinline__ short8 ld8(const bf16* p) { return *(const short8*)p; }

// ===== MFMA GEMM: Y[b][oc][n] = sum_ic W[oc][ic] * X[b][ic][n] ===== (unchanged, passing)
template <typename TX, typename TY>
__global__ __launch_bounds__(256) void gemm_mfma(
    const bf16* __restrict__ Wb, const TX* __restrict__ X, TY* __restrict__ Y, int IC) {
  __shared__ short smA[8192];
  __shared__ short smB[8192];
  int tid = threadIdx.x;
  int lane = tid & 63, w = tid >> 6;
  int wm = w >> 1, wn = w & 1;
  int n0 = blockIdx.x * 128, oc0 = blockIdx.y * 128, b = blockIdx.z;
  const TX* Xb = X + (size_t)b * IC * N_;
  TY* Yb = Y + (size_t)b * (gridDim.y * 128) * N_;
  f32x4 acc[4][4] = {};
  int nB = tid & 127;
  int gB0 = tid >> 7;

  for (int k0 = 0; k0 < IC; k0 += 64) {
    short8 areg[4], breg[4];
#pragma unroll
    for (int i = 0; i < 4; i++) {
      int q = i * 256 + tid;
      int rowA = q >> 3, gA = q & 7;
      areg[i] = ld8(Wb + (size_t)(oc0 + rowA) * IC + k0 + gA * 8);
      int gB = i * 2 + gB0;
      const TX* src = Xb + (size_t)(k0 + gB * 8) * N_ + n0 + nB;
      short8 v;
#pragma unroll
      for (int j = 0; j < 8; j++) v[j] = rawbf(src[(size_t)j * N_]);
      breg[i] = v;
    }
    __syncthreads();
#pragma unroll
    for (int i = 0; i < 4; i++) {
      int q = i * 256 + tid;
      int rowA = q >> 3, gA = q & 7;
      *(short8*)&smA[rowA * 64 + ((gA ^ (rowA & 7)) * 8)] = areg[i];
      int gB = i * 2 + gB0;
      *(short8*)&smB[nB * 64 + ((gB ^ (nB & 7)) * 8)] = breg[i];
    }
    __syncthreads();
#pragma unroll
    for (int ks = 0; ks < 2; ks++) {
      int gk = ks * 4 + (lane >> 4);
      short8 af[4], bfr[4];
#pragma unroll
      for (int mf = 0; mf < 4; mf++) {
        int row = wm * 64 + mf * 16 + (lane & 15);
        af[mf] = *(const short8*)&smA[row * 64 + ((gk ^ (row & 7)) * 8)];
      }
#pragma unroll
      for (int nf = 0; nf < 4; nf++) {
        int nr = wn * 64 + nf * 16 + (lane & 15);
        bfr[nf] = *(const short8*)&smB[nr * 64 + ((gk ^ (nr & 7)) * 8)];
      }
#pragma unroll
      for (int nf = 0; nf < 4; nf++)
#pragma unroll
        for (int mf = 0; mf < 4; mf++)
          acc[mf][nf] = __builtin_amdgcn_mfma_f32_16x16x32_bf16(af[mf], bfr[nf], acc[mf][nf], 0, 0, 0);
    }
    __syncthreads();
  }
#pragma unroll
  for (int mf = 0; mf < 4; mf++)
#pragma unroll
    for (int nf = 0; nf < 4; nf++) {
      int ocr = oc0 + wm * 64 + mf * 16 + ((lane >> 4) << 2);
      int nc = n0 + wn * 64 + nf * 16 + (lane & 15);
#pragma unroll
      for (int j = 0; j < 4; j++)
        storeF(&Yb[(size_t)(ocr + j) * N_ + nc], acc[mf][nf][j]);
    }
}

// ================= weight f32 -> bf16 =================
__global__ __launch_bounds__(256) void k_cvt(const float* __restrict__ s,
                                             bf16* __restrict__ d, int n) {
  int i = blockIdx.x * 256 + threadIdx.x;
  if (i < n) d[i] = __float2bfloat16(s[i]);
}

// ================= LP: adaptive avg pool per region =================
__global__ __launch_bounds__(256) void k_lp_pool(const bf16* __restrict__ qkv,
                                                 float* __restrict__ pools) {
  int b = blockIdx.z, cc = blockIdx.y, r = blockIdx.x;
  int g = cc >> 6;
  const int S[4] = {1, 2, 3, 6};
  int s = S[g];
  if (r >= s * s) return;
  int i = r / s, j = r % s;
  int h0 = (i * H_) / s, h1 = ((i + 1) * H_ + s - 1) / s;
  int w0 = (j * W_) / s, w1 = ((j + 1) * W_ + s - 1) / s;
  int vch = 512 + (cc & 31) * 8 + (cc >> 5);
  const bf16* src = qkv + ((size_t)b * 768 + vch) * N_;
  int wlen = w1 - w0;
  int cnt = (h1 - h0) * wlen;
  float sum = 0.f;
  for (int idx = threadIdx.x; idx < cnt; idx += 256) {
    int yy = h0 + idx / wlen;
    int xx = w0 + idx % wlen;
    sum += toF(src[yy * W_ + xx]);
  }
  __shared__ float red[256];
  red[threadIdx.x] = sum;
  __syncthreads();
  for (int off = 128; off > 0; off >>= 1) {
    if (threadIdx.x < off) red[threadIdx.x] += red[threadIdx.x + off];
    __syncthreads();
  }
  if (threadIdx.x == 0) pools[((size_t)b * 256 + cc) * 36 + r] = red[0] / (float)cnt;
}

// ======== HP conv body: KSZ x KSZ depthwise over LDS patch, 4 cols/thread ========
template <int KSZ>
__device__ __forceinline__ void hp_conv(const float (*patch)[136], const float* wsm,
                                        int r, int cg, float acc[4]) {
  constexpr int OFF = 3 - KSZ / 2;
#pragma unroll
  for (int u = 0; u < KSZ; u++) {
    const float* row = &patch[r + u + OFF][cg * 4];
    float val[12];
    *(float4*)&val[0] = *(const float4*)&row[0];
    *(float4*)&val[4] = *(const float4*)&row[4];
    *(float4*)&val[8] = *(const float4*)&row[8];
#pragma unroll
    for (int v = 0; v < KSZ; v++) {
      float wv = wsm[u * KSZ + v];
#pragma unroll
      for (int j = 0; j < 4; j++) acc[j] += val[j + v + OFF] * wv;
    }
  }
}

// ======== fused: HP depthwise conv (LDS-tiled) + LP bilinear-up(relu) + df = q*HP+LP ====
__global__ __launch_bounds__(256) void k_dffuse(const bf16* __restrict__ qkv,
    const float* __restrict__ pools,
    const float* __restrict__ f3w, const float* __restrict__ f3b,
    const float* __restrict__ f5w, const float* __restrict__ f5b,
    const float* __restrict__ f7w, const float* __restrict__ f7b,
    bf16* __restrict__ df) {
  int b = blockIdx.z, cc = blockIdx.y, ty0 = blockIdx.x * 8;
  __shared__ float patch[14][136];
  __shared__ float wsm[49];
  int tid = threadIdx.x;
  int vch = 512 + (cc & 31) * 8 + (cc >> 5);   // v in (d,h) channel decomposition
  const bf16* src = qkv + ((size_t)b * 768 + vch) * N_;
  int ksz; const float* wp; float bias;
  if (cc < 64)       { ksz = 3; wp = f3w + cc * 9;          bias = f3b[cc]; }
  else if (cc < 160) { ksz = 5; wp = f5w + (cc - 64) * 25;  bias = f5b[cc - 64]; }
  else               { ksz = 7; wp = f7w + (cc - 160) * 49; bias = f7b[cc - 160]; }
  if (tid < ksz * ksz) wsm[tid] = wp[tid];
  // patch: py 0..13 <-> gy = ty0-3+py ; px 0..135 <-> gx = px-3 ; zero pad
  for (int idx = tid; idx < 14 * 136; idx += 256) {
    int py = idx / 136, px = idx % 136;
    int gy = ty0 - 3 + py, gx = px - 3;
    float v = 0.f;
    if (gy >= 0 && gy < H_ && gx >= 0 && gx < W_) v = toF(src[gy * W_ + gx]);
    patch[py][px] = v;
  }
  __syncthreads();
  int r = tid & 7, cg = tid >> 3;
  int y = ty0 + r;
  float acc[4] = {bias, bias, bias, bias};
  if (cc < 64)       hp_conv<3>(patch, wsm, r, cg, acc);
  else if (cc < 160) hp_conv<5>(patch, wsm, r, cg, acc);
  else               hp_conv<7>(patch, wsm, r, cg, acc);
  // LP bilinear + df
  const int S[4] = {1, 2, 3, 6};
  int s = S[cc >> 6];
  const float* pl = pools + ((size_t)b * 256 + cc) * 36;
  int qch = (cc & 31) * 8 + (cc >> 5);
  const bf16* qsrc = qkv + ((size_t)b * 768 + qch) * N_;
  s16x4 qv = *(const s16x4*)&qsrc[y * W_ + cg * 4];
  s16x4 ov;
#pragma unroll
  for (int j = 0; j < 4; j++) {
    int x = cg * 4 + j;
    float fy = (y + 0.5f) * s * (1.0f / 128.f) - 0.5f;
    float fx = (x + 0.5f) * s * (1.0f / 128.f) - 0.5f;
    int i0 = (int)floorf(fy); float ty = fy - i0;
    int j0 = (int)floorf(fx); float tx = fx - j0;
    int i1 = i0 + 1, j1 = j0 + 1;
    i0 = min(max(i0, 0), s - 1); i1 = min(max(i1, 0), s - 1);
    j0 = min(max(j0, 0), s - 1); j1 = min(max(j1, 0), s - 1);
    float v00 = pl[i0 * s + j0], v01 = pl[i0 * s + j1];
    float v10 = pl[i1 * s + j0], v11 = pl[i1 * s + j1];
    float lp = (1.f - ty) * ((1.f - tx) * v00 + tx * v01) + ty * ((1.f - tx) * v10 + tx * v11);
    lp = fmaxf(lp, 0.f);
    ov[j] = rawbf(bfs2f(qv[j]) * acc[j] + lp);
  }
  *(s16x4*)&df[((size_t)b * 256 + cc) * N_ + y * W_ + cg * 4] = ov;
}

// ======== window attention (unchanged, passing) ========
__global__ __launch_bounds__(256) void k_attn(const bf16* __restrict__ qkv,
    bf16* __restrict__ df, const float* __restrict__ rel) {
  int b = blockIdx.z, head = blockIdx.y, win = blockIdx.x;
  int wh = win >> 4, wc = win & 15;
  __shared__ float qs[64][33], ks[64][33], ds[64][33];
  __shared__ float pm[64][65];
  __shared__ float bias_s[225];
  int tid = threadIdx.x;
  for (int i = tid; i < 225; i += 256) bias_s[i] = rel[i * 8 + head];
  int dc = tid >> 3, c2 = tid & 7;
  const bf16* qsrc = qkv + ((size_t)b * 768 + head * 32 + dc) * N_;
  const bf16* ksrc = qkv + ((size_t)b * 768 + 256 + head * 32 + dc) * N_;
  const bf16* dsrc = df + ((size_t)b * 256 + head * 32 + dc) * N_;
#pragma unroll
  for (int r = 0; r < 8; r++) {
    int n = (wh * 8 + r) * W_ + wc * 8 + c2;
    int l = r * 8 + c2;
    qs[l][dc] = toF(qsrc[n]);
    ks[l][dc] = toF(ksrc[n]);
    ds[l][dc] = toF(dsrc[n]);
  }
  __syncthreads();
  int l = tid >> 2, mg = tid & 3;
  int r1 = l >> 3, c1 = l & 7;
  const float scale = 0.17677669529663687f;
  float vals[16];
  float mymax = -1e30f;
#pragma unroll
  for (int mi = 0; mi < 16; mi++) {
    int m = mg * 16 + mi;
    float a = 0.f;
#pragma unroll
    for (int kk = 0; kk < 32; kk++) a += qs[l][kk] * ks[m][kk];
    int r2 = m >> 3, c2m = m & 7;
    a = a * scale + bias_s[(r1 - r2 + 7) * 15 + (c1 - c2m + 7)];
    vals[mi] = a;
    mymax = fmaxf(mymax, a);
  }
  mymax = fmaxf(mymax, __shfl_xor(mymax, 1));
  mymax = fmaxf(mymax, __shfl_xor(mymax, 2));
  float mysum = 0.f;
#pragma unroll
  for (int mi = 0; mi < 16; mi++) { vals[mi] = __expf(vals[mi] - mymax); mysum += vals[mi]; }
  mysum += __shfl_xor(mysum, 1);
  mysum += __shfl_xor(mysum, 2);
  float inv = 1.0f / mysum;
#pragma unroll
  for (int mi = 0; mi < 16; mi++) pm[l][mg * 16 + mi] = vals[mi] * inv;
  __syncthreads();
  int dg = tid & 3;
  float acc[8] = {};
  for (int m = 0; m < 64; m++) {
    float p = pm[l][m];
#pragma unroll
    for (int q2 = 0; q2 < 8; q2++) acc[q2] += p * ds[m][dg * 8 + q2];
  }
  int n = (wh * 8 + r1) * W_ + wc * 8 + c1;
#pragma unroll
  for (int q2 = 0; q2 < 8; q2++)
    df[((size_t)b * 256 + head * 32 + dg * 8 + q2) * N_ + n] = __float2bfloat16(acc[q2]);
}

// ================= CBAM: per-channel max/mean (short8 vectorized) =================
__global__ __launch_bounds__(256) void k_chstats(const bf16* __restrict__ loc,
    float* __restrict__ mx, float* __restrict__ av) {
  int c = blockIdx.x, b = blockIdx.y;
  const bf16* p = loc + ((size_t)b * 512 + c) * N_;
  int tid = threadIdx.x;
  float m = -1e30f, s = 0.f;
  for (int i = tid * 8; i < N_; i += 2048) {
    short8 v = *(const short8*)&p[i];
#pragma unroll
    for (int j = 0; j < 8; j++) { float f = bfs2f(v[j]); m = fmaxf(m, f); s += f; }
  }
  __shared__ float rm[256], rs[256];
  rm[tid] = m; rs[tid] = s;
  __syncthreads();
  for (int off = 128; off > 0; off >>= 1) {
    if (tid < off) {
      rm[tid] = fmaxf(rm[tid], rm[tid + off]);
      rs[tid] += rs[tid + off];
    }
    __syncthreads();
  }
  if (tid == 0) { mx[b * 512 + c] = rm[0]; av[b * 512 + c] = rs[0] / (float)N_; }
}

// ================= CBAM channel MLPs (coalesced, shfl-reduced) =================
__global__ __launch_bounds__(256) void k_mlp(const float* __restrict__ mx,
    const float* __restrict__ av,
    const float* __restrict__ w1m, const float* __restrict__ b1m,
    const float* __restrict__ w2m, const float* __restrict__ b2m,
    const float* __restrict__ w1a, const float* __restrict__ b1a,
    const float* __restrict__ w2a, const float* __restrict__ b2a,
    float* __restrict__ svec) {
  __shared__ float hm[4][256], ha[4][256];
  int tid = threadIdx.x, lane = tid & 63, wvi = tid >> 6;
  for (int bb = 0; bb < 4; bb++) {
    for (int jj = 0; jj < 64; jj++) {
      int j = wvi * 64 + jj;
      float am = 0.f, aa = 0.f;
#pragma unroll
      for (int t = 0; t < 8; t++) {
        int i = lane + t * 64;
        am += mx[bb * 512 + i] * w1m[j * 512 + i];
        aa += av[bb * 512 + i] * w1a[j * 512 + i];
      }
#pragma unroll
      for (int off = 32; off > 0; off >>= 1) {
        am += __shfl_xor(am, off);
        aa += __shfl_xor(aa, off);
      }
      if (lane == 0) {
        hm[bb][j] = fmaxf(am + b1m[j], 0.f);
        ha[bb][j] = fmaxf(aa + b1a[j], 0.f);
      }
    }
  }
  __syncthreads();
  for (int bb = 0; bb < 4; bb++) {
    for (int oo = 0; oo < 128; oo++) {
      int o = wvi * 128 + oo;
      float sm = 0.f, sa = 0.f;
#pragma unroll
      for (int t = 0; t < 4; t++) {
        int jj = lane + t * 64;
        sm += hm[bb][jj] * w2m[o * 256 + jj];
        sa += ha[bb][jj] * w2a[o * 256 + jj];
      }
#pragma unroll
      for (int off = 32; off > 0; off >>= 1) {
        sm += __shfl_xor(sm, off);
        sa += __shfl_xor(sa, off);
      }
      if (lane == 0) {
        float wm = 1.f / (1.f + __expf(-(sm + b2m[o])));
        float wa = 1.f / (1.f + __expf(-(sa + b2a[o])));
        svec[bb * 512 + o] = 1.f / (1.f + __expf(-(wm + wa)));
      }
    }
  }
}

// ================= spatial-attn input: per-pixel max/mean (2 px/thread) ===========
__global__ __launch_bounds__(256) void k_cat(const bf16* __restrict__ loc,
    const float* __restrict__ svec, float* __restrict__ catmax, float* __restrict__ catmean) {
  int b = blockIdx.y;
  int n2 = (blockIdx.x * 256 + threadIdx.x) * 2;
  const bf16* lb = loc + (size_t)b * 512 * N_;
  const float* sv = svec + b * 512;
  float m0 = -1e30f, m1 = -1e30f, s0 = 0.f, s1 = 0.f;
#pragma unroll 4
  for (int c = 0; c < 512; c++) {
    unsigned u = *(const unsigned*)&lb[(size_t)c * N_ + n2];
    float sc = sv[c];
    float f0 = __builtin_bit_cast(float, u << 16) * sc;
    float f1 = __builtin_bit_cast(float, u & 0xffff0000u) * sc;
    m0 = fmaxf(m0, f0); s0 += f0;
    m1 = fmaxf(m1, f1); s1 += f1;
  }
  catmax[b * N_ + n2] = m0;     catmax[b * N_ + n2 + 1] = m1;
  catmean[b * N_ + n2] = s0 * (1.f / 512.f);
  catmean[b * N_ + n2 + 1] = s1 * (1.f / 512.f);
}

// ================= spatial attention 7x7 conv -> sigmoid (unchanged) =================
__global__ __launch_bounds__(256) void k_sa(const float* __restrict__ catmax,
    const float* __restrict__ catmean, const float* __restrict__ saw,
    const float* __restrict__ sab, float* __restrict__ samap) {
  int b = blockIdx.y;
  int n = blockIdx.x * 256 + threadIdx.x;
  int y = n >> 7, x = n & 127;
  float acc = sab[0];
  for (int u = 0; u < 7; u++) {
    int yy = y + u - 3;
    if (yy < 0 || yy >= H_) continue;
    for (int v = 0; v < 7; v++) {
      int xx = x + v - 3;
      if (xx < 0 || xx >= W_) continue;
      int nn = b * N_ + yy * W_ + xx;
      acc += catmax[nn] * saw[u * 7 + v] + catmean[nn] * saw[49 + u * 7 + v];
    }
  }
  samap[b * N_ + n] = 1.f / (1.f + __expf(-acc));
}

// ================= scale loc in place (short8 vectorized) =================
__global__ __launch_bounds__(256) void k_locscale(bf16* __restrict__ loc,
    const float* __restrict__ svec, const float* __restrict__ samap) {
  int b = blockIdx.z, c = blockIdx.y;
  int n0 = (blockIdx.x * 256 + threadIdx.x) * 8;
  float sc = svec[b * 512 + c];
  bf16* p = loc + ((size_t)b * 512 + c) * N_ + n0;
  const float* sm = samap + b * N_ + n0;
  short8 v = *(const short8*)p;
  float4 sa = *(const float4*)&sm[0];
  float4 sb = *(const float4*)&sm[4];
  float smv[8] = {sa.x, sa.y, sa.z, sa.w, sb.x, sb.y, sb.z, sb.w};
  short8 o;
#pragma unroll
  for (int j = 0; j < 8; j++) o[j] = rawbf(bfs2f(v[j]) * sc * smv[j]);
  *(short8*)p = o;
}

// ======== directional avg pools + local add — LDS-tiled ========
__global__ __launch_bounds__(256) void k_out1(const bf16* __restrict__ img,
    const bf16* __restrict__ locout, bf16* __restrict__ out1) {
  int b = blockIdx.z, c = blockIdx.y, ty0 = blockIdx.x * 8;
  __shared__ float patch[15][136];
  int tid = threadIdx.x;
  const bf16* p = img + ((size_t)b * 256 + c) * N_;
  for (int idx = tid; idx < 15 * 136; idx += 256) {
    int py = idx / 136, px = idx % 136;
    int gy = ty0 - 3 + py, gx = px - 3;
    float v = 0.f;
    if (gy >= 0 && gy <= 128 && gx >= 0 && gx <= 128) {
      int yy = (gy == 128) ? 126 : gy;
      int xx = (gx == 128) ? 126 : gx;
      v = toF(p[yy * W_ + xx]);
    }
    patch[py][px] = v;
  }
  __syncthreads();
  int r = tid & 7, cg = tid >> 3;
  int y = ty0 + r;
  // horizontal taps: row y, cols x+t  (px = cg*4 + j + v)
  float val[12];
  const float* row = &patch[r + 3][cg * 4];
  *(float4*)&val[0] = *(const float4*)&row[0];
  *(float4*)&val[4] = *(const float4*)&row[4];
  *(float4*)&val[8] = *(const float4*)&row[8];
  float sh[4] = {};
#pragma unroll
  for (int v = 0; v < 8; v++)
#pragma unroll
    for (int j = 0; j < 4; j++) sh[j] += val[j + v];
  // vertical taps: col x, rows y+t  (py = r+u, px = cg*4+3+j)
  float sv[4] = {};
#pragma unroll
  for (int u = 0; u < 8; u++)
#pragma unroll
    for (int j = 0; j < 4; j++) sv[j] += patch[r + u][cg * 4 + 3 + j];
  size_t o = ((size_t)b * 256 + c) * N_ + y * W_ + cg * 4;
  s16x4 lo = *(const s16x4*)&locout[o];
  s16x4 ov;
#pragma unroll
  for (int j = 0; j < 4; j++) ov[j] = rawbf(0.125f * (sv[j] + sh[j]) + bfs2f(lo[j]));
  *(s16x4*)&out1[o] = ov;
}

// ======== depthwise 8x8 + BN — LDS-tiled ========
__global__ __launch_bounds__(256) void k_dw(const bf16* __restrict__ out1,
    const float* __restrict__ dww, const float* __restrict__ bng,
    const float* __restrict__ bnb, bf16* __restrict__ dwo) {
  int b = blockIdx.z, c = blockIdx.y, ty0 = blockIdx.x * 8;
  __shared__ float patch[15][136];
  __shared__ float wsm[64];
  int tid = threadIdx.x;
  const bf16* p = out1 + ((size_t)b * 256 + c) * N_;
  if (tid < 64) wsm[tid] = dww[c * 64 + tid];
  for (int idx = tid; idx < 15 * 136; idx += 256) {
    int py = idx / 136, px = idx % 136;
    int gy = ty0 - 3 + py, gx = px - 3;
    float v = 0.f;
    if (gy >= 0 && gy <= 128 && gx >= 0 && gx <= 128) {
      int yy = (gy == 128) ? 126 : gy;
      int xx = (gx == 128) ? 126 : gx;
      v = toF(p[yy * W_ + xx]);
    }
    patch[py][px] = v;
  }
  __syncthreads();
  int r = tid & 7, cg = tid >> 3;
  float acc[4] = {};
#pragma unroll
  for (int u = 0; u < 8; u++) {
    const float* row = &patch[r + u][cg * 4];
    float val[12];
    *(float4*)&val[0] = *(const float4*)&row[0];
    *(float4*)&val[4] = *(const float4*)&row[4];
    *(float4*)&val[8] = *(const float4*)&row[8];
#pragma unroll
    for (int v = 0; v < 8; v++) {
      float wv = wsm[u * 8 + v];
#pragma unroll
      for (int j = 0; j < 4; j++) acc[j] += val[j + v] * wv;
    }
  }
  float g = bng[c] * rsqrtf(1.0f + 1e-5f);
  float bb = bnb[c];
  int y = ty0 + r;
  s16x4 ov;
#pragma unroll
  for (int j = 0; j < 4; j++) ov[j] = rawbf(acc[j] * g + bb);
  *(s16x4*)&dwo[((size_t)b * 256 + c) * N_ + y * W_ + cg * 4] = ov;
}

// =========================== launcher ===========================
extern "C" void kernel_launch(void* const* d_in, const int* in_sizes, int n_in,
                              void* d_out, int out_size, void* d_ws, size_t ws_size,
                              hipStream_t stream) {
  const float* x        = (const float*)d_in[0];
  const float* qkv_w    = (const float*)d_in[1];
  const float* ld1_w    = (const float*)d_in[2];
  const float* ld2_w    = (const float*)d_in[3];
  const float* camax_w1 = (const float*)d_in[4];
  const float* camax_b1 = (const float*)d_in[5];
  const float* camax_w2 = (const float*)d_in[6];
  const float* camax_b2 = (const float*)d_in[7];
  const float* caavg_w1 = (const float*)d_in[8];
  const float* caavg_b1 = (const float*)d_in[9];
  const float* caavg_w2 = (const float*)d_in[10];
  const float* caavg_b2 = (const float*)d_in[11];
  const float* sa_w     = (const float*)d_in[12];
  const float* sa_b     = (const float*)d_in[13];
  const float* f3_w     = (const float*)d_in[14];
  const float* f3_b     = (const float*)d_in[15];
  const float* f5_w     = (const float*)d_in[16];
  const float* f5_b     = (const float*)d_in[17];
  const float* f7_w     = (const float*)d_in[18];
  const float* f7_b     = (const float*)d_in[19];
  const float* rel_tab  = (const float*)d_in[20];
  const float* dw_w     = (const float*)d_in[21];
  const float* bn_g     = (const float*)d_in[22];
  const float* bn_b     = (const float*)d_in[23];
  const float* pw_w     = (const float*)d_in[24];
  float* out = (float*)d_out;

  // ---- arena (byte offsets), peak ~130 MiB ----
  char* wsb = (char*)d_ws;
  bf16* qkvb   = (bf16*)(wsb);                    // [4][768][16384] bf16 = 96 MiB
  bf16* dfb    = (bf16*)(wsb + 100663296);        // 32 MiB (df -> img in-place)
  bf16* locb   = (bf16*)(wsb);                    // 64 MiB (qkv dead)
  bf16* locout = (bf16*)(wsb + 67108864);         // 32 MiB
  bf16* out1   = (bf16*)(wsb);                    // 32 MiB (locb dead)
  bf16* dwo    = (bf16*)(wsb + 33554432);         // 32 MiB
  float* small = (float*)(wsb + 134217728);
  float* pools   = small;                         // [4][256][36]
  float* mx      = small + 36864;                 // [4][512]
  float* av      = small + 38912;                 // [4][512]
  float* svec    = small + 40960;                 // [4][512]
  float* catmax  = small + 43008;                 // [4][16384]
  float* catmean = small + 108544;                // [4][16384]
  float* samap   = small + 174080;                // [4][16384]
  bf16* wq  = (bf16*)(wsb + 135176192);           // 768*256
  bf16* wl1 = wq  + 196608;                       // 512*256
  bf16* wl2 = wl1 + 131072;                       // 256*512
  bf16* wpw = wl2 + 131072;                       // 256*256

  dim3 blk(256);
  k_cvt<<<dim3(768), blk, 0, stream>>>(qkv_w, wq, 196608);
  k_cvt<<<dim3(512), blk, 0, stream>>>(ld1_w, wl1, 131072);
  k_cvt<<<dim3(512), blk, 0, stream>>>(ld2_w, wl2, 131072);
  k_cvt<<<dim3(256), blk, 0, stream>>>(pw_w, wpw, 65536);

  // attention / filter branch
  gemm_mfma<float, bf16><<<dim3(128, 6, 4), blk, 0, stream>>>(wq, x, qkvb, 256);
  k_lp_pool<<<dim3(36, 256, 4), blk, 0, stream>>>(qkvb, pools);
  k_dffuse<<<dim3(16, 256, 4), blk, 0, stream>>>(qkvb, pools, f3_w, f3_b, f5_w, f5_b,
                                                 f7_w, f7_b, dfb);
  k_attn<<<dim3(256, 8, 4), blk, 0, stream>>>(qkvb, dfb, rel_tab);
  // local (CBAM) branch
  gemm_mfma<float, bf16><<<dim3(128, 4, 4), blk, 0, stream>>>(wl1, x, locb, 256);
  k_chstats<<<dim3(512, 4), blk, 0, stream>>>(locb, mx, av);
  k_mlp<<<dim3(1), blk, 0, stream>>>(mx, av, camax_w1, camax_b1, camax_w2, camax_b2,
                                     caavg_w1, caavg_b1, caavg_w2, caavg_b2, svec);
  k_cat<<<dim3(32, 4), blk, 0, stream>>>(locb, svec, catmax, catmean);
  k_sa<<<dim3(64, 4), blk, 0, stream>>>(catmax, catmean, sa_w, sa_b, samap);
  k_locscale<<<dim3(8, 512, 4), blk, 0, stream>>>(locb, svec, samap);
  gemm_mfma<bf16, bf16><<<dim3(128, 2, 4), blk, 0, stream>>>(wl2, locb, locout, 512);
  // merge + projection
  k_out1<<<dim3(16, 256, 4), blk, 0, stream>>>(dfb, locout, out1);
  k_dw<<<dim3(16, 256, 4), blk, 0, stream>>>(out1, dw_w, bn_g, bn_b, dwo);
  gemm_mfma<bf16, float><<<dim3(128, 2, 4), blk, 0, stream>>>(wpw, dwo, out, 256);
}

// Round 6
// 718.730 us; speedup vs baseline: 3.4825x; 1.6826x over previous
//
#include <hip/hip_runtime.h>
#include <hip/hip_bf16.h>
#include <math.h>

#define B_ 4
#define H_ 128
#define W_ 128
#define N_ 16384

using bf16 = __hip_bfloat16;
typedef short short8 __attribute__((ext_vector_type(8)));
typedef short s16x4 __attribute__((ext_vector_type(4)));
typedef float f32x4 __attribute__((ext_vector_type(4)));

__device__ __forceinline__ float toF(float v) { return v; }
__device__ __forceinline__ float toF(bf16 v) { return __bfloat162float(v); }
__device__ __forceinline__ void storeF(float* p, float v) { *p = v; }
__device__ __forceinline__ void storeF(bf16* p, float v) { *p = __float2bfloat16(v); }

__device__ __forceinline__ unsigned short f2bf(float f) {
  unsigned u = __builtin_bit_cast(unsigned, f);
  unsigned r = (u + 0x7FFFu + ((u >> 16) & 1u)) >> 16;
  return (unsigned short)r;
}
__device__ __forceinline__ short rawbf(float v) { return (short)f2bf(v); }
__device__ __forceinline__ short rawbf(bf16 v) { return __builtin_bit_cast(short, v); }
__device__ __forceinline__ float bfs2f(short s) {
  return __builtin_bit_cast(float, ((unsigned)(unsigned short)s) << 16);
}

// load 8 contiguous bf16 as raw shorts
__device__ __forceinline__ short8 ld8(const bf16* p) { return *(const short8*)p; }

// ===== MFMA GEMM: Y[b][oc][n] = sum_ic W[oc][ic] * X[b][ic][n] ===== (unchanged, passing)
template <typename TX, typename TY>
__global__ __launch_bounds__(256) void gemm_mfma(
    const bf16* __restrict__ Wb, const TX* __restrict__ X, TY* __restrict__ Y, int IC) {
  __shared__ short smA[8192];
  __shared__ short smB[8192];
  int tid = threadIdx.x;
  int lane = tid & 63, w = tid >> 6;
  int wm = w >> 1, wn = w & 1;
  int n0 = blockIdx.x * 128, oc0 = blockIdx.y * 128, b = blockIdx.z;
  const TX* Xb = X + (size_t)b * IC * N_;
  TY* Yb = Y + (size_t)b * (gridDim.y * 128) * N_;
  f32x4 acc[4][4] = {};
  int nB = tid & 127;
  int gB0 = tid >> 7;

  for (int k0 = 0; k0 < IC; k0 += 64) {
    short8 areg[4], breg[4];
#pragma unroll
    for (int i = 0; i < 4; i++) {
      int q = i * 256 + tid;
      int rowA = q >> 3, gA = q & 7;
      areg[i] = ld8(Wb + (size_t)(oc0 + rowA) * IC + k0 + gA * 8);
      int gB = i * 2 + gB0;
      const TX* src = Xb + (size_t)(k0 + gB * 8) * N_ + n0 + nB;
      short8 v;
#pragma unroll
      for (int j = 0; j < 8; j++) v[j] = rawbf(src[(size_t)j * N_]);
      breg[i] = v;
    }
    __syncthreads();
#pragma unroll
    for (int i = 0; i < 4; i++) {
      int q = i * 256 + tid;
      int rowA = q >> 3, gA = q & 7;
      *(short8*)&smA[rowA * 64 + ((gA ^ (rowA & 7)) * 8)] = areg[i];
      int gB = i * 2 + gB0;
      *(short8*)&smB[nB * 64 + ((gB ^ (nB & 7)) * 8)] = breg[i];
    }
    __syncthreads();
#pragma unroll
    for (int ks = 0; ks < 2; ks++) {
      int gk = ks * 4 + (lane >> 4);
      short8 af[4], bfr[4];
#pragma unroll
      for (int mf = 0; mf < 4; mf++) {
        int row = wm * 64 + mf * 16 + (lane & 15);
        af[mf] = *(const short8*)&smA[row * 64 + ((gk ^ (row & 7)) * 8)];
      }
#pragma unroll
      for (int nf = 0; nf < 4; nf++) {
        int nr = wn * 64 + nf * 16 + (lane & 15);
        bfr[nf] = *(const short8*)&smB[nr * 64 + ((gk ^ (nr & 7)) * 8)];
      }
#pragma unroll
      for (int nf = 0; nf < 4; nf++)
#pragma unroll
        for (int mf = 0; mf < 4; mf++)
          acc[mf][nf] = __builtin_amdgcn_mfma_f32_16x16x32_bf16(af[mf], bfr[nf], acc[mf][nf], 0, 0, 0);
    }
    __syncthreads();
  }
#pragma unroll
  for (int mf = 0; mf < 4; mf++)
#pragma unroll
    for (int nf = 0; nf < 4; nf++) {
      int ocr = oc0 + wm * 64 + mf * 16 + ((lane >> 4) << 2);
      int nc = n0 + wn * 64 + nf * 16 + (lane & 15);
#pragma unroll
      for (int j = 0; j < 4; j++)
        storeF(&Yb[(size_t)(ocr + j) * N_ + nc], acc[mf][nf][j]);
    }
}

// ================= weight f32 -> bf16 =================
__global__ __launch_bounds__(256) void k_cvt(const float* __restrict__ s,
                                             bf16* __restrict__ d, int n) {
  int i = blockIdx.x * 256 + threadIdx.x;
  if (i < n) d[i] = __float2bfloat16(s[i]);
}

// ================= LP: adaptive avg pool per region =================
__global__ __launch_bounds__(256) void k_lp_pool(const bf16* __restrict__ qkv,
                                                 float* __restrict__ pools) {
  int b = blockIdx.z, cc = blockIdx.y, r = blockIdx.x;
  int g = cc >> 6;
  const int S[4] = {1, 2, 3, 6};
  int s = S[g];
  if (r >= s * s) return;
  int i = r / s, j = r % s;
  int h0 = (i * H_) / s, h1 = ((i + 1) * H_ + s - 1) / s;
  int w0 = (j * W_) / s, w1 = ((j + 1) * W_ + s - 1) / s;
  int vch = 512 + (cc & 31) * 8 + (cc >> 5);
  const bf16* src = qkv + ((size_t)b * 768 + vch) * N_;
  int wlen = w1 - w0;
  int cnt = (h1 - h0) * wlen;
  float sum = 0.f;
  for (int idx = threadIdx.x; idx < cnt; idx += 256) {
    int yy = h0 + idx / wlen;
    int xx = w0 + idx % wlen;
    sum += toF(src[yy * W_ + xx]);
  }
  __shared__ float red[256];
  red[threadIdx.x] = sum;
  __syncthreads();
  for (int off = 128; off > 0; off >>= 1) {
    if (threadIdx.x < off) red[threadIdx.x] += red[threadIdx.x + off];
    __syncthreads();
  }
  if (threadIdx.x == 0) pools[((size_t)b * 256 + cc) * 36 + r] = red[0] / (float)cnt;
}

// ======== HP conv body: KSZ x KSZ depthwise over LDS patch, 4 cols/thread ========
template <int KSZ>
__device__ __forceinline__ void hp_conv(const float (*patch)[136], const float* wsm,
                                        int r, int cg, float acc[4]) {
  constexpr int OFF = 3 - KSZ / 2;
#pragma unroll
  for (int u = 0; u < KSZ; u++) {
    const float* row = &patch[r + u + OFF][cg * 4];
    float val[12];
    *(float4*)&val[0] = *(const float4*)&row[0];
    *(float4*)&val[4] = *(const float4*)&row[4];
    *(float4*)&val[8] = *(const float4*)&row[8];
#pragma unroll
    for (int v = 0; v < KSZ; v++) {
      float wv = wsm[u * KSZ + v];
#pragma unroll
      for (int j = 0; j < 4; j++) acc[j] += val[j + v + OFF] * wv;
    }
  }
}

// ======== fused: HP depthwise conv (LDS-tiled) + LP bilinear-up(relu) + df = q*HP+LP ====
__global__ __launch_bounds__(256) void k_dffuse(const bf16* __restrict__ qkv,
    const float* __restrict__ pools,
    const float* __restrict__ f3w, const float* __restrict__ f3b,
    const float* __restrict__ f5w, const float* __restrict__ f5b,
    const float* __restrict__ f7w, const float* __restrict__ f7b,
    bf16* __restrict__ df) {
  int b = blockIdx.z, cc = blockIdx.y, ty0 = blockIdx.x * 8;
  __shared__ float patch[14][136];
  __shared__ float wsm[49];
  int tid = threadIdx.x;
  int vch = 512 + (cc & 31) * 8 + (cc >> 5);   // v in (d,h) channel decomposition
  const bf16* src = qkv + ((size_t)b * 768 + vch) * N_;
  int ksz; const float* wp; float bias;
  if (cc < 64)       { ksz = 3; wp = f3w + cc * 9;          bias = f3b[cc]; }
  else if (cc < 160) { ksz = 5; wp = f5w + (cc - 64) * 25;  bias = f5b[cc - 64]; }
  else               { ksz = 7; wp = f7w + (cc - 160) * 49; bias = f7b[cc - 160]; }
  if (tid < ksz * ksz) wsm[tid] = wp[tid];
  for (int idx = tid; idx < 14 * 136; idx += 256) {
    int py = idx / 136, px = idx % 136;
    int gy = ty0 - 3 + py, gx = px - 3;
    float v = 0.f;
    if (gy >= 0 && gy < H_ && gx >= 0 && gx < W_) v = toF(src[gy * W_ + gx]);
    patch[py][px] = v;
  }
  __syncthreads();
  int r = tid & 7, cg = tid >> 3;
  int y = ty0 + r;
  float acc[4] = {bias, bias, bias, bias};
  if (cc < 64)       hp_conv<3>(patch, wsm, r, cg, acc);
  else if (cc < 160) hp_conv<5>(patch, wsm, r, cg, acc);
  else               hp_conv<7>(patch, wsm, r, cg, acc);
  const int S[4] = {1, 2, 3, 6};
  int s = S[cc >> 6];
  const float* pl = pools + ((size_t)b * 256 + cc) * 36;
  int qch = (cc & 31) * 8 + (cc >> 5);
  const bf16* qsrc = qkv + ((size_t)b * 768 + qch) * N_;
  s16x4 qv = *(const s16x4*)&qsrc[y * W_ + cg * 4];
  s16x4 ov;
#pragma unroll
  for (int j = 0; j < 4; j++) {
    int x = cg * 4 + j;
    float fy = (y + 0.5f) * s * (1.0f / 128.f) - 0.5f;
    float fx = (x + 0.5f) * s * (1.0f / 128.f) - 0.5f;
    int i0 = (int)floorf(fy); float ty = fy - i0;
    int j0 = (int)floorf(fx); float tx = fx - j0;
    int i1 = i0 + 1, j1 = j0 + 1;
    i0 = min(max(i0, 0), s - 1); i1 = min(max(i1, 0), s - 1);
    j0 = min(max(j0, 0), s - 1); j1 = min(max(j1, 0), s - 1);
    float v00 = pl[i0 * s + j0], v01 = pl[i0 * s + j1];
    float v10 = pl[i1 * s + j0], v11 = pl[i1 * s + j1];
    float lp = (1.f - ty) * ((1.f - tx) * v00 + tx * v01) + ty * ((1.f - tx) * v10 + tx * v11);
    lp = fmaxf(lp, 0.f);
    ov[j] = rawbf(bfs2f(qv[j]) * acc[j] + lp);
  }
  *(s16x4*)&df[((size_t)b * 256 + cc) * N_ + y * W_ + cg * 4] = ov;
}

// ======== window attention (unchanged, passing) ========
__global__ __launch_bounds__(256) void k_attn(const bf16* __restrict__ qkv,
    bf16* __restrict__ df, const float* __restrict__ rel) {
  int b = blockIdx.z, head = blockIdx.y, win = blockIdx.x;
  int wh = win >> 4, wc = win & 15;
  __shared__ float qs[64][33], ks[64][33], ds[64][33];
  __shared__ float pm[64][65];
  __shared__ float bias_s[225];
  int tid = threadIdx.x;
  for (int i = tid; i < 225; i += 256) bias_s[i] = rel[i * 8 + head];
  int dc = tid >> 3, c2 = tid & 7;
  const bf16* qsrc = qkv + ((size_t)b * 768 + head * 32 + dc) * N_;
  const bf16* ksrc = qkv + ((size_t)b * 768 + 256 + head * 32 + dc) * N_;
  const bf16* dsrc = df + ((size_t)b * 256 + head * 32 + dc) * N_;
#pragma unroll
  for (int r = 0; r < 8; r++) {
    int n = (wh * 8 + r) * W_ + wc * 8 + c2;
    int l = r * 8 + c2;
    qs[l][dc] = toF(qsrc[n]);
    ks[l][dc] = toF(ksrc[n]);
    ds[l][dc] = toF(dsrc[n]);
  }
  __syncthreads();
  int l = tid >> 2, mg = tid & 3;
  int r1 = l >> 3, c1 = l & 7;
  const float scale = 0.17677669529663687f;
  float vals[16];
  float mymax = -1e30f;
#pragma unroll
  for (int mi = 0; mi < 16; mi++) {
    int m = mg * 16 + mi;
    float a = 0.f;
#pragma unroll
    for (int kk = 0; kk < 32; kk++) a += qs[l][kk] * ks[m][kk];
    int r2 = m >> 3, c2m = m & 7;
    a = a * scale + bias_s[(r1 - r2 + 7) * 15 + (c1 - c2m + 7)];
    vals[mi] = a;
    mymax = fmaxf(mymax, a);
  }
  mymax = fmaxf(mymax, __shfl_xor(mymax, 1));
  mymax = fmaxf(mymax, __shfl_xor(mymax, 2));
  float mysum = 0.f;
#pragma unroll
  for (int mi = 0; mi < 16; mi++) { vals[mi] = __expf(vals[mi] - mymax); mysum += vals[mi]; }
  mysum += __shfl_xor(mysum, 1);
  mysum += __shfl_xor(mysum, 2);
  float inv = 1.0f / mysum;
#pragma unroll
  for (int mi = 0; mi < 16; mi++) pm[l][mg * 16 + mi] = vals[mi] * inv;
  __syncthreads();
  int dg = tid & 3;
  float acc[8] = {};
  for (int m = 0; m < 64; m++) {
    float p = pm[l][m];
#pragma unroll
    for (int q2 = 0; q2 < 8; q2++) acc[q2] += p * ds[m][dg * 8 + q2];
  }
  int n = (wh * 8 + r1) * W_ + wc * 8 + c1;
#pragma unroll
  for (int q2 = 0; q2 < 8; q2++)
    df[((size_t)b * 256 + head * 32 + dg * 8 + q2) * N_ + n] = __float2bfloat16(acc[q2]);
}

// ================= CBAM: per-channel max/mean (short8 vectorized) =================
__global__ __launch_bounds__(256) void k_chstats(const bf16* __restrict__ loc,
    float* __restrict__ mx, float* __restrict__ av) {
  int c = blockIdx.x, b = blockIdx.y;
  const bf16* p = loc + ((size_t)b * 512 + c) * N_;
  int tid = threadIdx.x;
  float m = -1e30f, s = 0.f;
  for (int i = tid * 8; i < N_; i += 2048) {
    short8 v = *(const short8*)&p[i];
#pragma unroll
    for (int j = 0; j < 8; j++) { float f = bfs2f(v[j]); m = fmaxf(m, f); s += f; }
  }
  __shared__ float rm[256], rs[256];
  rm[tid] = m; rs[tid] = s;
  __syncthreads();
  for (int off = 128; off > 0; off >>= 1) {
    if (tid < off) {
      rm[tid] = fmaxf(rm[tid], rm[tid + off]);
      rs[tid] += rs[tid + off];
    }
    __syncthreads();
  }
  if (tid == 0) { mx[b * 512 + c] = rm[0]; av[b * 512 + c] = rs[0] / (float)N_; }
}

// ========== CBAM MLP layer 1 (wide): hidden[path][b][j] = relu(W1 @ stats + b1) =========
__global__ __launch_bounds__(256) void k_mlp1(const float* __restrict__ mx,
    const float* __restrict__ av,
    const float* __restrict__ w1m, const float* __restrict__ b1m,
    const float* __restrict__ w1a, const float* __restrict__ b1a,
    float* __restrict__ hidden) {
  int path = blockIdx.z, b = blockIdx.y, j0 = blockIdx.x * 64;
  const float* stats = (path ? av : mx) + b * 512;
  const float* w1 = path ? w1a : w1m;
  const float* b1 = path ? b1a : b1m;
  int tid = threadIdx.x, lane = tid & 63, wv = tid >> 6;
#pragma unroll
  for (int jj = 0; jj < 16; jj++) {
    int j = j0 + wv * 16 + jj;
    float a = 0.f;
#pragma unroll
    for (int t = 0; t < 8; t++) {
      int i = lane + t * 64;
      a += stats[i] * w1[j * 512 + i];
    }
#pragma unroll
    for (int off = 32; off > 0; off >>= 1) a += __shfl_xor(a, off);
    if (lane == 0) hidden[(path * 4 + b) * 256 + j] = fmaxf(a + b1[j], 0.f);
  }
}

// ========== CBAM MLP layer 2 (wide): svec = sigmoid(sig(L2m) + sig(L2a)) =========
__global__ __launch_bounds__(256) void k_mlp2(const float* __restrict__ hidden,
    const float* __restrict__ w2m, const float* __restrict__ b2m,
    const float* __restrict__ w2a, const float* __restrict__ b2a,
    float* __restrict__ svec) {
  int b = blockIdx.y, o0 = blockIdx.x * 64;
  const float* hm = hidden + b * 256;
  const float* ha = hidden + (4 + b) * 256;
  int tid = threadIdx.x, lane = tid & 63, wv = tid >> 6;
#pragma unroll
  for (int oo = 0; oo < 16; oo++) {
    int o = o0 + wv * 16 + oo;
    float sm = 0.f, sa = 0.f;
#pragma unroll
    for (int t = 0; t < 4; t++) {
      int jj = lane + t * 64;
      sm += hm[jj] * w2m[o * 256 + jj];
      sa += ha[jj] * w2a[o * 256 + jj];
    }
#pragma unroll
    for (int off = 32; off > 0; off >>= 1) {
      sm += __shfl_xor(sm, off);
      sa += __shfl_xor(sa, off);
    }
    if (lane == 0) {
      float wm = 1.f / (1.f + __expf(-(sm + b2m[o])));
      float wa = 1.f / (1.f + __expf(-(sa + b2a[o])));
      svec[b * 512 + o] = 1.f / (1.f + __expf(-(wm + wa)));
    }
  }
}

// ================= spatial-attn input: per-pixel max/mean (2 px/thread) ===========
__global__ __launch_bounds__(256) void k_cat(const bf16* __restrict__ loc,
    const float* __restrict__ svec, float* __restrict__ catmax, float* __restrict__ catmean) {
  int b = blockIdx.y;
  int n2 = (blockIdx.x * 256 + threadIdx.x) * 2;
  const bf16* lb = loc + (size_t)b * 512 * N_;
  const float* sv = svec + b * 512;
  float m0 = -1e30f, m1 = -1e30f, s0 = 0.f, s1 = 0.f;
#pragma unroll 4
  for (int c = 0; c < 512; c++) {
    unsigned u = *(const unsigned*)&lb[(size_t)c * N_ + n2];
    float sc = sv[c];
    float f0 = __builtin_bit_cast(float, u << 16) * sc;
    float f1 = __builtin_bit_cast(float, u & 0xffff0000u) * sc;
    m0 = fmaxf(m0, f0); s0 += f0;
    m1 = fmaxf(m1, f1); s1 += f1;
  }
  catmax[b * N_ + n2] = m0;     catmax[b * N_ + n2 + 1] = m1;
  catmean[b * N_ + n2] = s0 * (1.f / 512.f);
  catmean[b * N_ + n2 + 1] = s1 * (1.f / 512.f);
}

// ================= spatial attention 7x7 conv -> sigmoid (unchanged) =================
__global__ __launch_bounds__(256) void k_sa(const float* __restrict__ catmax,
    const float* __restrict__ catmean, const float* __restrict__ saw,
    const float* __restrict__ sab, float* __restrict__ samap) {
  int b = blockIdx.y;
  int n = blockIdx.x * 256 + threadIdx.x;
  int y = n >> 7, x = n & 127;
  float acc = sab[0];
  for (int u = 0; u < 7; u++) {
    int yy = y + u - 3;
    if (yy < 0 || yy >= H_) continue;
    for (int v = 0; v < 7; v++) {
      int xx = x + v - 3;
      if (xx < 0 || xx >= W_) continue;
      int nn = b * N_ + yy * W_ + xx;
      acc += catmax[nn] * saw[u * 7 + v] + catmean[nn] * saw[49 + u * 7 + v];
    }
  }
  samap[b * N_ + n] = 1.f / (1.f + __expf(-acc));
}

// ================= scale loc in place (short8 vectorized) =================
__global__ __launch_bounds__(256) void k_locscale(bf16* __restrict__ loc,
    const float* __restrict__ svec, const float* __restrict__ samap) {
  int b = blockIdx.z, c = blockIdx.y;
  int n0 = (blockIdx.x * 256 + threadIdx.x) * 8;
  float sc = svec[b * 512 + c];
  bf16* p = loc + ((size_t)b * 512 + c) * N_ + n0;
  const float* sm = samap + b * N_ + n0;
  short8 v = *(const short8*)p;
  float4 sa = *(const float4*)&sm[0];
  float4 sb = *(const float4*)&sm[4];
  float smv[8] = {sa.x, sa.y, sa.z, sa.w, sb.x, sb.y, sb.z, sb.w};
  short8 o;
#pragma unroll
  for (int j = 0; j < 8; j++) o[j] = rawbf(bfs2f(v[j]) * sc * smv[j]);
  *(short8*)p = o;
}

// ======== directional avg pools + local add — LDS-tiled ========
__global__ __launch_bounds__(256) void k_out1(const bf16* __restrict__ img,
    const bf16* __restrict__ locout, bf16* __restrict__ out1) {
  int b = blockIdx.z, c = blockIdx.y, ty0 = blockIdx.x * 8;
  __shared__ float patch[15][136];
  int tid = threadIdx.x;
  const bf16* p = img + ((size_t)b * 256 + c) * N_;
  for (int idx = tid; idx < 15 * 136; idx += 256) {
    int py = idx / 136, px = idx % 136;
    int gy = ty0 - 3 + py, gx = px - 3;
    float v = 0.f;
    if (gy >= 0 && gy <= 128 && gx >= 0 && gx <= 128) {
      int yy = (gy == 128) ? 126 : gy;
      int xx = (gx == 128) ? 126 : gx;
      v = toF(p[yy * W_ + xx]);
    }
    patch[py][px] = v;
  }
  __syncthreads();
  int r = tid & 7, cg = tid >> 3;
  int y = ty0 + r;
  float val[12];
  const float* row = &patch[r + 3][cg * 4];
  *(float4*)&val[0] = *(const float4*)&row[0];
  *(float4*)&val[4] = *(const float4*)&row[4];
  *(float4*)&val[8] = *(const float4*)&row[8];
  float sh[4] = {};
#pragma unroll
  for (int v = 0; v < 8; v++)
#pragma unroll
    for (int j = 0; j < 4; j++) sh[j] += val[j + v];
  float sv[4] = {};
#pragma unroll
  for (int u = 0; u < 8; u++)
#pragma unroll
    for (int j = 0; j < 4; j++) sv[j] += patch[r + u][cg * 4 + 3 + j];
  size_t o = ((size_t)b * 256 + c) * N_ + y * W_ + cg * 4;
  s16x4 lo = *(const s16x4*)&locout[o];
  s16x4 ov;
#pragma unroll
  for (int j = 0; j < 4; j++) ov[j] = rawbf(0.125f * (sv[j] + sh[j]) + bfs2f(lo[j]));
  *(s16x4*)&out1[o] = ov;
}

// ======== depthwise 8x8 + BN — LDS-tiled ========
__global__ __launch_bounds__(256) void k_dw(const bf16* __restrict__ out1,
    const float* __restrict__ dww, const float* __restrict__ bng,
    const float* __restrict__ bnb, bf16* __restrict__ dwo) {
  int b = blockIdx.z, c = blockIdx.y, ty0 = blockIdx.x * 8;
  __shared__ float patch[15][136];
  __shared__ float wsm[64];
  int tid = threadIdx.x;
  const bf16* p = out1 + ((size_t)b * 256 + c) * N_;
  if (tid < 64) wsm[tid] = dww[c * 64 + tid];
  for (int idx = tid; idx < 15 * 136; idx += 256) {
    int py = idx / 136, px = idx % 136;
    int gy = ty0 - 3 + py, gx = px - 3;
    float v = 0.f;
    if (gy >= 0 && gy <= 128 && gx >= 0 && gx <= 128) {
      int yy = (gy == 128) ? 126 : gy;
      int xx = (gx == 128) ? 126 : gx;
      v = toF(p[yy * W_ + xx]);
    }
    patch[py][px] = v;
  }
  __syncthreads();
  int r = tid & 7, cg = tid >> 3;
  float acc[4] = {};
#pragma unroll
  for (int u = 0; u < 8; u++) {
    const float* row = &patch[r + u][cg * 4];
    float val[12];
    *(float4*)&val[0] = *(const float4*)&row[0];
    *(float4*)&val[4] = *(const float4*)&row[4];
    *(float4*)&val[8] = *(const float4*)&row[8];
#pragma unroll
    for (int v = 0; v < 8; v++) {
      float wv = wsm[u * 8 + v];
#pragma unroll
      for (int j = 0; j < 4; j++) acc[j] += val[j + v] * wv;
    }
  }
  float g = bng[c] * rsqrtf(1.0f + 1e-5f);
  float bb = bnb[c];
  int y = ty0 + r;
  s16x4 ov;
#pragma unroll
  for (int j = 0; j < 4; j++) ov[j] = rawbf(acc[j] * g + bb);
  *(s16x4*)&dwo[((size_t)b * 256 + c) * N_ + y * W_ + cg * 4] = ov;
}

// =========================== launcher ===========================
extern "C" void kernel_launch(void* const* d_in, const int* in_sizes, int n_in,
                              void* d_out, int out_size, void* d_ws, size_t ws_size,
                              hipStream_t stream) {
  const float* x        = (const float*)d_in[0];
  const float* qkv_w    = (const float*)d_in[1];
  const float* ld1_w    = (const float*)d_in[2];
  const float* ld2_w    = (const float*)d_in[3];
  const float* camax_w1 = (const float*)d_in[4];
  const float* camax_b1 = (const float*)d_in[5];
  const float* camax_w2 = (const float*)d_in[6];
  const float* camax_b2 = (const float*)d_in[7];
  const float* caavg_w1 = (const float*)d_in[8];
  const float* caavg_b1 = (const float*)d_in[9];
  const float* caavg_w2 = (const float*)d_in[10];
  const float* caavg_b2 = (const float*)d_in[11];
  const float* sa_w     = (const float*)d_in[12];
  const float* sa_b     = (const float*)d_in[13];
  const float* f3_w     = (const float*)d_in[14];
  const float* f3_b     = (const float*)d_in[15];
  const float* f5_w     = (const float*)d_in[16];
  const float* f5_b     = (const float*)d_in[17];
  const float* f7_w     = (const float*)d_in[18];
  const float* f7_b     = (const float*)d_in[19];
  const float* rel_tab  = (const float*)d_in[20];
  const float* dw_w     = (const float*)d_in[21];
  const float* bn_g     = (const float*)d_in[22];
  const float* bn_b     = (const float*)d_in[23];
  const float* pw_w     = (const float*)d_in[24];
  float* out = (float*)d_out;

  // ---- arena (byte offsets), peak ~130 MiB ----
  char* wsb = (char*)d_ws;
  bf16* qkvb   = (bf16*)(wsb);                    // [4][768][16384] bf16 = 96 MiB
  bf16* dfb    = (bf16*)(wsb + 100663296);        // 32 MiB (df -> img in-place)
  bf16* locb   = (bf16*)(wsb);                    // 64 MiB (qkv dead)
  bf16* locout = (bf16*)(wsb + 67108864);         // 32 MiB
  bf16* out1   = (bf16*)(wsb);                    // 32 MiB (locb dead)
  bf16* dwo    = (bf16*)(wsb + 33554432);         // 32 MiB
  float* small = (float*)(wsb + 134217728);
  float* pools   = small;                         // [4][256][36]
  float* mx      = small + 36864;                 // [4][512]
  float* av      = small + 38912;                 // [4][512]
  float* svec    = small + 40960;                 // [4][512]
  float* catmax  = small + 43008;                 // [4][16384]
  float* catmean = small + 108544;                // [4][16384]
  float* samap   = small + 174080;                // [4][16384]
  float* hidden  = catmax;                        // [2][4][256] — dead before k_cat writes
  bf16* wq  = (bf16*)(wsb + 135176192);           // 768*256
  bf16* wl1 = wq  + 196608;                       // 512*256
  bf16* wl2 = wl1 + 131072;                       // 256*512
  bf16* wpw = wl2 + 131072;                       // 256*256

  dim3 blk(256);
  k_cvt<<<dim3(768), blk, 0, stream>>>(qkv_w, wq, 196608);
  k_cvt<<<dim3(512), blk, 0, stream>>>(ld1_w, wl1, 131072);
  k_cvt<<<dim3(512), blk, 0, stream>>>(ld2_w, wl2, 131072);
  k_cvt<<<dim3(256), blk, 0, stream>>>(pw_w, wpw, 65536);

  // attention / filter branch
  gemm_mfma<float, bf16><<<dim3(128, 6, 4), blk, 0, stream>>>(wq, x, qkvb, 256);
  k_lp_pool<<<dim3(36, 256, 4), blk, 0, stream>>>(qkvb, pools);
  k_dffuse<<<dim3(16, 256, 4), blk, 0, stream>>>(qkvb, pools, f3_w, f3_b, f5_w, f5_b,
                                                 f7_w, f7_b, dfb);
  k_attn<<<dim3(256, 8, 4), blk, 0, stream>>>(qkvb, dfb, rel_tab);
  // local (CBAM) branch
  gemm_mfma<float, bf16><<<dim3(128, 4, 4), blk, 0, stream>>>(wl1, x, locb, 256);
  k_chstats<<<dim3(512, 4), blk, 0, stream>>>(locb, mx, av);
  k_mlp1<<<dim3(4, 4, 2), blk, 0, stream>>>(mx, av, camax_w1, camax_b1,
                                            caavg_w1, caavg_b1, hidden);
  k_mlp2<<<dim3(8, 4), blk, 0, stream>>>(hidden, camax_w2, camax_b2,
                                         caavg_w2, caavg_b2, svec);
  k_cat<<<dim3(32, 4), blk, 0, stream>>>(locb, svec, catmax, catmean);
  k_sa<<<dim3(64, 4), blk, 0, stream>>>(catmax, catmean, sa_w, sa_b, samap);
  k_locscale<<<dim3(8, 512, 4), blk, 0, stream>>>(locb, svec, samap);
  gemm_mfma<bf16, bf16><<<dim3(128, 2, 4), blk, 0, stream>>>(wl2, locb, locout, 512);
  // merge + projection
  k_out1<<<dim3(16, 256, 4), blk, 0, stream>>>(dfb, locout, out1);
  k_dw<<<dim3(16, 256, 4), blk, 0, stream>>>(out1, dw_w, bn_g, bn_b, dwo);
  gemm_mfma<bf16, float><<<dim3(128, 2, 4), blk, 0, stream>>>(wpw, dwo, out, 256);
}